// Round 1
// baseline (1416.488 us; speedup 1.0000x reference)
//
#include <hip/hip_runtime.h>

// ---------- float <-> order-preserving uint key (for atomicMax on floats) ----
__device__ __forceinline__ unsigned fkey(float f) {
  unsigned b = __float_as_uint(f);
  return (b & 0x80000000u) ? ~b : (b | 0x80000000u);
}
__device__ __forceinline__ float funkey(unsigned u) {
  unsigned b = (u & 0x80000000u) ? (u & 0x7FFFFFFFu) : ~u;
  return __uint_as_float(b);
}

// ---------- Layer 1 edge phase: agg1[dst] += relu(x[src] + ea*we1 + be1) ----
__global__ void edge1_kernel(const float* __restrict__ x, const int* __restrict__ src,
                             const int* __restrict__ dst, const float* __restrict__ ea,
                             const float* __restrict__ we1, const float* __restrict__ be1,
                             float* __restrict__ agg1, int E) {
  int j = blockIdx.x * blockDim.x + threadIdx.x;
  if (j >= E) return;
  float a = ea[j];
  int s = src[j], d = dst[j];
#pragma unroll
  for (int f = 0; f < 9; ++f) {
    float m = fmaf(a, we1[f], be1[f]) + x[s * 9 + f];
    m = fmaxf(m, 0.0f);
    atomicAdd(&agg1[d * 9 + f], m);
  }
}

// ---------- Layer 1 node MLP: h1 = relu(relu((x+agg1)@w11+b11)@w12+b12) -----
__global__ void node1_kernel(const float* __restrict__ x, const float* __restrict__ agg1,
                             const float* __restrict__ w11, const float* __restrict__ b11,
                             const float* __restrict__ w12, const float* __restrict__ b12,
                             float* __restrict__ h1, int N) {
  __shared__ float sW1[9 * 64];
  __shared__ float sB1[64];
  __shared__ float sW2[64 * 64];
  __shared__ float sB2[64];
  for (int t = threadIdx.x; t < 9 * 64; t += blockDim.x) sW1[t] = w11[t];
  for (int t = threadIdx.x; t < 64; t += blockDim.x) { sB1[t] = b11[t]; sB2[t] = b12[t]; }
  for (int t = threadIdx.x; t < 64 * 64; t += blockDim.x) sW2[t] = w12[t];
  __syncthreads();
  int i = blockIdx.x * blockDim.x + threadIdx.x;
  if (i >= N) return;
  float xin[9];
#pragma unroll
  for (int k = 0; k < 9; ++k) xin[k] = x[i * 9 + k] + agg1[i * 9 + k];
  float t1[64];
#pragma unroll
  for (int o = 0; o < 64; ++o) {
    float acc = sB1[o];
#pragma unroll
    for (int k = 0; k < 9; ++k) acc = fmaf(xin[k], sW1[k * 64 + o], acc);
    t1[o] = fmaxf(acc, 0.0f);
  }
  for (int o = 0; o < 64; ++o) {
    float acc = sB2[o];
#pragma unroll
    for (int k = 0; k < 64; ++k) acc = fmaf(t1[k], sW2[k * 64 + o], acc);
    h1[i * 64 + o] = fmaxf(acc, 0.0f);
  }
}

// ---------- Layer 2 edge phase: one thread per (edge, feature) --------------
__global__ void edge2_kernel(const float* __restrict__ h1, const int* __restrict__ src,
                             const int* __restrict__ dst, const float* __restrict__ ea,
                             const float* __restrict__ we2, const float* __restrict__ be2,
                             float* __restrict__ agg2, int E) {
  int t = blockIdx.x * blockDim.x + threadIdx.x;
  int j = t >> 6;
  int f = t & 63;
  if (j >= E) return;
  float a = ea[j];
  int s = src[j], d = dst[j];
  float m = fmaf(a, we2[f], be2[f]) + h1[s * 64 + f];
  m = fmaxf(m, 0.0f);
  atomicAdd(&agg2[d * 64 + f], m);
}

// ---------- Layer 2 node MLP + readout: raw[i] ------------------------------
__global__ void node2_kernel(const float* __restrict__ h1, const float* __restrict__ agg2,
                             const float* __restrict__ w21, const float* __restrict__ b21,
                             const float* __restrict__ w22, const float* __restrict__ b22,
                             const float* __restrict__ wr1, const float* __restrict__ br1,
                             const float* __restrict__ wr2, const float* __restrict__ br2,
                             float* __restrict__ raw, int N) {
  __shared__ float sW1[64 * 64];
  __shared__ float sB1[64];
  __shared__ float sW2[64 * 64];
  __shared__ float sB2[64];
  __shared__ float sWr1[64 * 32];
  __shared__ float sBr1[32];
  __shared__ float sWr2[32];
  __shared__ float sBr2;
  for (int t = threadIdx.x; t < 64 * 64; t += blockDim.x) { sW1[t] = w21[t]; sW2[t] = w22[t]; }
  for (int t = threadIdx.x; t < 64; t += blockDim.x) { sB1[t] = b21[t]; sB2[t] = b22[t]; }
  for (int t = threadIdx.x; t < 64 * 32; t += blockDim.x) sWr1[t] = wr1[t];
  for (int t = threadIdx.x; t < 32; t += blockDim.x) { sBr1[t] = br1[t]; sWr2[t] = wr2[t]; }
  if (threadIdx.x == 0) sBr2 = br2[0];
  __syncthreads();
  int i = blockIdx.x * blockDim.x + threadIdx.x;
  if (i >= N) return;
  float hin[64];
#pragma unroll
  for (int k = 0; k < 64; ++k) hin[k] = h1[i * 64 + k] + agg2[i * 64 + k];
  float a1[64];
  for (int o = 0; o < 64; ++o) {
    float acc = sB1[o];
#pragma unroll
    for (int k = 0; k < 64; ++k) acc = fmaf(hin[k], sW1[k * 64 + o], acc);
    a1[o] = fmaxf(acc, 0.0f);
  }
  float a2[64];
  for (int o = 0; o < 64; ++o) {
    float acc = sB2[o];
#pragma unroll
    for (int k = 0; k < 64; ++k) acc = fmaf(a1[k], sW2[k * 64 + o], acc);
    a2[o] = fmaxf(acc, 0.0f);
  }
  float r[32];
  for (int o = 0; o < 32; ++o) {
    float acc = sBr1[o];
#pragma unroll
    for (int k = 0; k < 64; ++k) acc = fmaf(a2[k], sWr1[k * 32 + o], acc);
    r[o] = fmaxf(acc, 0.0f);
  }
  float acc = sBr2;
#pragma unroll
  for (int k = 0; k < 32; ++k) acc = fmaf(r[k], sWr2[k], acc);
  raw[i] = acc;
}

// ---------- Segment softmax (3 small kernels over N=100k) -------------------
__global__ void segmax_kernel(const float* __restrict__ raw, const int* __restrict__ batch,
                              unsigned* __restrict__ gmax, int N) {
  int i = blockIdx.x * blockDim.x + threadIdx.x;
  if (i >= N) return;
  atomicMax(&gmax[batch[i]], fkey(raw[i]));
}

__global__ void expsum_kernel(const float* __restrict__ raw, const int* __restrict__ batch,
                              const unsigned* __restrict__ gmax, float* __restrict__ z,
                              float* __restrict__ gsum, int N) {
  int i = blockIdx.x * blockDim.x + threadIdx.x;
  if (i >= N) return;
  int b = batch[i];
  float zz = __expf(raw[i] - funkey(gmax[b]));
  zz = expf(raw[i] - funkey(gmax[b]));  // use precise expf for accuracy
  z[i] = zz;
  atomicAdd(&gsum[b], zz);
}

__global__ void final_kernel(const float* __restrict__ z, const int* __restrict__ batch,
                             const float* __restrict__ gsum, const float* __restrict__ Btot,
                             float* __restrict__ out, int N) {
  int i = blockIdx.x * blockDim.x + threadIdx.x;
  if (i >= N) return;
  int b = batch[i];
  out[i] = z[i] / gsum[b] * Btot[b];
}

extern "C" void kernel_launch(void* const* d_in, const int* in_sizes, int n_in,
                              void* d_out, int out_size, void* d_ws, size_t ws_size,
                              hipStream_t stream) {
  const float* x     = (const float*)d_in[0];
  const int* eidx    = (const int*)d_in[1];
  const float* eattr = (const float*)d_in[2];
  const int* batch   = (const int*)d_in[3];
  const float* Btot  = (const float*)d_in[4];
  const float* we1 = (const float*)d_in[5];
  const float* be1 = (const float*)d_in[6];
  const float* w11 = (const float*)d_in[7];
  const float* b11 = (const float*)d_in[8];
  const float* w12 = (const float*)d_in[9];
  const float* b12 = (const float*)d_in[10];
  const float* we2 = (const float*)d_in[11];
  const float* be2 = (const float*)d_in[12];
  const float* w21 = (const float*)d_in[13];
  const float* b21 = (const float*)d_in[14];
  const float* w22 = (const float*)d_in[15];
  const float* b22 = (const float*)d_in[16];
  const float* wr1 = (const float*)d_in[17];
  const float* br1 = (const float*)d_in[18];
  const float* wr2 = (const float*)d_in[19];
  const float* br2 = (const float*)d_in[20];

  const int N  = in_sizes[0] / 9;     // 100000
  const int E  = in_sizes[2];         // 1600000 (edge_attr is E x 1)
  const int NG = in_sizes[4];         // 1000
  const int* src = eidx;
  const int* dst = eidx + E;

  float* ws = (float*)d_ws;
  float* agg1 = ws;                        // N*9
  float* h1   = agg1 + (size_t)N * 9;      // N*64
  float* agg2 = h1 + (size_t)N * 64;       // N*64
  float* raw  = agg2 + (size_t)N * 64;     // N
  float* z    = raw + N;                   // N
  unsigned* gmax = (unsigned*)(z + N);     // NG
  float* gsum = (float*)(gmax + NG);       // NG

  // zero accumulators (gmax=0 is the key-space minimum: every segment non-empty)
  hipMemsetAsync(agg1, 0, (size_t)N * 9 * sizeof(float), stream);
  hipMemsetAsync(agg2, 0, (size_t)N * 64 * sizeof(float), stream);
  hipMemsetAsync(gmax, 0, (size_t)NG * 2 * sizeof(float), stream);  // gmax + gsum

  dim3 blk(256);

  edge1_kernel<<<dim3((E + 255) / 256), blk, 0, stream>>>(x, src, dst, eattr, we1, be1, agg1, E);
  node1_kernel<<<dim3((N + 255) / 256), blk, 0, stream>>>(x, agg1, w11, b11, w12, b12, h1, N);

  long long tot2 = (long long)E * 64;
  edge2_kernel<<<dim3((unsigned)((tot2 + 255) / 256)), blk, 0, stream>>>(h1, src, dst, eattr, we2, be2, agg2, E);
  node2_kernel<<<dim3((N + 255) / 256), blk, 0, stream>>>(h1, agg2, w21, b21, w22, b22,
                                                          wr1, br1, wr2, br2, raw, N);

  segmax_kernel<<<dim3((N + 255) / 256), blk, 0, stream>>>(raw, batch, gmax, N);
  expsum_kernel<<<dim3((N + 255) / 256), blk, 0, stream>>>(raw, batch, gmax, z, gsum, N);
  final_kernel<<<dim3((N + 255) / 256), blk, 0, stream>>>(z, batch, gsum, Btot, (float*)d_out, N);
}

// Round 2
// 1193.440 us; speedup vs baseline: 1.1869x; 1.1869x over previous
//
#include <hip/hip_runtime.h>

// ---------- float <-> order-preserving uint key (for atomicMax on floats) ----
__device__ __forceinline__ unsigned fkey(float f) {
  unsigned b = __float_as_uint(f);
  return (b & 0x80000000u) ? ~b : (b | 0x80000000u);
}
__device__ __forceinline__ float funkey(unsigned u) {
  unsigned b = (u & 0x80000000u) ? (u & 0x7FFFFFFFu) : ~u;
  return __uint_as_float(b);
}

// ---------- CSR build ---------------------------------------------------------
__global__ void deg_kernel(const int* __restrict__ dst, int* __restrict__ deg, int E) {
  int j = blockIdx.x * blockDim.x + threadIdx.x;
  if (j < E) atomicAdd(&deg[dst[j]], 1);
}

// single-block exclusive scan (N=100k, ~98 elems/thread)
__global__ void scan_kernel(const int* __restrict__ deg, int* __restrict__ rowptr, int N, int E) {
  __shared__ int partial[1024];
  int t = threadIdx.x;
  int per = (N + 1023) >> 10;
  int start = t * per, end = min(start + per, N);
  int sum = 0;
  for (int p = start; p < end; ++p) sum += deg[p];
  partial[t] = sum;
  __syncthreads();
  if (t == 0) {
    int run = 0;
    for (int i = 0; i < 1024; ++i) { int v = partial[i]; partial[i] = run; run += v; }
  }
  __syncthreads();
  int run = partial[t];
  for (int p = start; p < end; ++p) { rowptr[p] = run; run += deg[p]; }
  if (t == 0) rowptr[N] = E;
}

__global__ void scatter_kernel(const int* __restrict__ src, const int* __restrict__ dst,
                               const float* __restrict__ ea, int* __restrict__ cursor,
                               int* __restrict__ esrc, float* __restrict__ eea, int E) {
  int j = blockIdx.x * blockDim.x + threadIdx.x;
  if (j >= E) return;
  int d = dst[j];
  int pos = atomicAdd(&cursor[d], 1);
  esrc[pos] = src[j];
  eea[pos] = ea[j];
}

// ---------- Layer 1 fused: gather-agg + MLP (thread per node) ----------------
__global__ void node1_fused(const float* __restrict__ x, const int* __restrict__ rowptr,
                            const int* __restrict__ esrc, const float* __restrict__ eea,
                            const float* __restrict__ we1, const float* __restrict__ be1,
                            const float* __restrict__ w11, const float* __restrict__ b11,
                            const float* __restrict__ w12, const float* __restrict__ b12,
                            float* __restrict__ h1, int N) {
  __shared__ float sW1[9 * 64];
  __shared__ float sB1[64];
  __shared__ float sW2[64 * 64];
  __shared__ float sB2[64];
  for (int t = threadIdx.x; t < 9 * 64; t += blockDim.x) sW1[t] = w11[t];
  for (int t = threadIdx.x; t < 64; t += blockDim.x) { sB1[t] = b11[t]; sB2[t] = b12[t]; }
  for (int t = threadIdx.x; t < 64 * 64; t += blockDim.x) sW2[t] = w12[t];
  __syncthreads();
  int i = blockIdx.x * blockDim.x + threadIdx.x;
  if (i >= N) return;

  float we[9], be[9];
#pragma unroll
  for (int f = 0; f < 9; ++f) { we[f] = we1[f]; be[f] = be1[f]; }
  float acc[9];
#pragma unroll
  for (int f = 0; f < 9; ++f) acc[f] = 0.0f;

  int p0 = rowptr[i], p1 = rowptr[i + 1];
  for (int p = p0; p < p1; ++p) {
    int s = esrc[p];
    float a = eea[p];
#pragma unroll
    for (int f = 0; f < 9; ++f) {
      float m = fmaf(a, we[f], be[f]) + x[s * 9 + f];
      acc[f] += fmaxf(m, 0.0f);
    }
  }
  float xin[9];
#pragma unroll
  for (int f = 0; f < 9; ++f) xin[f] = x[i * 9 + f] + acc[f];

  float t1[64];
#pragma unroll
  for (int o = 0; o < 64; ++o) {
    float a = sB1[o];
#pragma unroll
    for (int k = 0; k < 9; ++k) a = fmaf(xin[k], sW1[k * 64 + o], a);
    t1[o] = fmaxf(a, 0.0f);
  }
  for (int o = 0; o < 64; ++o) {
    float a = sB2[o];
#pragma unroll
    for (int k = 0; k < 64; ++k) a = fmaf(t1[k], sW2[k * 64 + o], a);
    h1[(size_t)i * 64 + o] = fmaxf(a, 0.0f);
  }
}

// ---------- Layer 2 fused: wave-per-node gather-agg + MLP + readout ----------
__global__ void __launch_bounds__(256) layer2_fused(
    const float* __restrict__ h1, const int* __restrict__ rowptr,
    const int* __restrict__ esrc, const float* __restrict__ eea,
    const float* __restrict__ we2, const float* __restrict__ be2,
    const float* __restrict__ w21, const float* __restrict__ b21,
    const float* __restrict__ w22, const float* __restrict__ b22,
    const float* __restrict__ wr1, const float* __restrict__ br1,
    const float* __restrict__ wr2, const float* __restrict__ br2,
    float* __restrict__ raw, int N) {
  __shared__ float sW1[64 * 64];
  __shared__ float sW2[64 * 64];
  __shared__ float sWr1[64 * 32];
  __shared__ float sB1[64];
  __shared__ float sB2[64];
  __shared__ float sBr1[32];
  __shared__ float sWr2[32];
  __shared__ float buf[4][2][64];  // per-wave ping-pong

  for (int t = threadIdx.x; t < 64 * 64; t += blockDim.x) { sW1[t] = w21[t]; sW2[t] = w22[t]; }
  for (int t = threadIdx.x; t < 64 * 32; t += blockDim.x) sWr1[t] = wr1[t];
  for (int t = threadIdx.x; t < 64; t += blockDim.x) { sB1[t] = b21[t]; sB2[t] = b22[t]; }
  for (int t = threadIdx.x; t < 32; t += blockDim.x) { sBr1[t] = br1[t]; sWr2[t] = wr2[t]; }
  __syncthreads();

  int wid = threadIdx.x >> 6;
  int lane = threadIdx.x & 63;
  int i = blockIdx.x * 4 + wid;
  bool valid = (i < N);

  float we_l = we2[lane], be_l = be2[lane];
  float acc = 0.0f;
  int p0 = 0, p1 = 0;
  if (valid) { p0 = rowptr[i]; p1 = rowptr[i + 1]; }
  for (int p = p0; p < p1; ++p) {
    int s = esrc[p];
    float a = eea[p];
    acc += fmaxf(fmaf(a, we_l, be_l) + h1[(size_t)s * 64 + lane], 0.0f);
  }
  float hin = valid ? (h1[(size_t)i * 64 + lane] + acc) : 0.0f;
  buf[wid][0][lane] = hin;
  __syncthreads();

  // stage 1: a1 = relu(hin @ w21 + b21)
  float a1 = sB1[lane];
#pragma unroll
  for (int k = 0; k < 64; ++k) a1 = fmaf(buf[wid][0][k], sW1[k * 64 + lane], a1);
  a1 = fmaxf(a1, 0.0f);
  __syncthreads();
  buf[wid][1][lane] = a1;
  __syncthreads();

  // stage 2: a2 = relu(a1 @ w22 + b22)
  float a2 = sB2[lane];
#pragma unroll
  for (int k = 0; k < 64; ++k) a2 = fmaf(buf[wid][1][k], sW2[k * 64 + lane], a2);
  a2 = fmaxf(a2, 0.0f);
  __syncthreads();
  buf[wid][0][lane] = a2;
  __syncthreads();

  // stage 3: readout r = relu(a2 @ wr1 + br1); val = r * wr2
  float val = 0.0f;
  if (lane < 32) {
    float r = sBr1[lane];
#pragma unroll
    for (int k = 0; k < 64; ++k) r = fmaf(buf[wid][0][k], sWr1[k * 32 + lane], r);
    r = fmaxf(r, 0.0f);
    val = r * sWr2[lane];
  }
#pragma unroll
  for (int off = 32; off >= 1; off >>= 1) val += __shfl_xor(val, off);
  if (valid && lane == 0) raw[i] = val + br2[0];
}

// ---------- Segment softmax --------------------------------------------------
__global__ void segmax_kernel(const float* __restrict__ raw, const int* __restrict__ batch,
                              unsigned* __restrict__ gmax, int N) {
  int i = blockIdx.x * blockDim.x + threadIdx.x;
  if (i >= N) return;
  atomicMax(&gmax[batch[i]], fkey(raw[i]));
}

__global__ void expsum_kernel(const float* __restrict__ raw, const int* __restrict__ batch,
                              const unsigned* __restrict__ gmax, float* __restrict__ z,
                              float* __restrict__ gsum, int N) {
  int i = blockIdx.x * blockDim.x + threadIdx.x;
  if (i >= N) return;
  int b = batch[i];
  float zz = expf(raw[i] - funkey(gmax[b]));
  z[i] = zz;
  atomicAdd(&gsum[b], zz);
}

__global__ void final_kernel(const float* __restrict__ z, const int* __restrict__ batch,
                             const float* __restrict__ gsum, const float* __restrict__ Btot,
                             float* __restrict__ out, int N) {
  int i = blockIdx.x * blockDim.x + threadIdx.x;
  if (i >= N) return;
  int b = batch[i];
  out[i] = z[i] / gsum[b] * Btot[b];
}

extern "C" void kernel_launch(void* const* d_in, const int* in_sizes, int n_in,
                              void* d_out, int out_size, void* d_ws, size_t ws_size,
                              hipStream_t stream) {
  const float* x     = (const float*)d_in[0];
  const int* eidx    = (const int*)d_in[1];
  const float* eattr = (const float*)d_in[2];
  const int* batch   = (const int*)d_in[3];
  const float* Btot  = (const float*)d_in[4];
  const float* we1 = (const float*)d_in[5];
  const float* be1 = (const float*)d_in[6];
  const float* w11 = (const float*)d_in[7];
  const float* b11 = (const float*)d_in[8];
  const float* w12 = (const float*)d_in[9];
  const float* b12 = (const float*)d_in[10];
  const float* we2 = (const float*)d_in[11];
  const float* be2 = (const float*)d_in[12];
  const float* w21 = (const float*)d_in[13];
  const float* b21 = (const float*)d_in[14];
  const float* w22 = (const float*)d_in[15];
  const float* b22 = (const float*)d_in[16];
  const float* wr1 = (const float*)d_in[17];
  const float* br1 = (const float*)d_in[18];
  const float* wr2 = (const float*)d_in[19];
  const float* br2 = (const float*)d_in[20];

  const int N  = in_sizes[0] / 9;     // 100000
  const int E  = in_sizes[2];         // 1600000
  const int NG = in_sizes[4];         // 1000
  const int* src = eidx;
  const int* dst = eidx + E;

  // workspace layout (all 4-byte elems)
  char* w = (char*)d_ws;
  int*   deg    = (int*)w;                 w += (size_t)N * 4;
  int*   rowptr = (int*)w;                 w += (size_t)(N + 1) * 4;
  int*   cursor = (int*)w;                 w += (size_t)N * 4;
  int*   esrc   = (int*)w;                 w += (size_t)E * 4;
  float* eea    = (float*)w;               w += (size_t)E * 4;
  float* h1     = (float*)w;               w += (size_t)N * 64 * 4;
  float* raw    = (float*)w;               w += (size_t)N * 4;
  float* z      = (float*)w;               w += (size_t)N * 4;
  unsigned* gmax = (unsigned*)w;           w += (size_t)NG * 4;
  float* gsum   = (float*)w;               w += (size_t)NG * 4;

  hipMemsetAsync(deg, 0, (size_t)N * 4, stream);
  hipMemsetAsync(gmax, 0, (size_t)NG * 8, stream);  // gmax + gsum (contiguous)

  dim3 blk(256);
  dim3 egrid((E + 255) / 256);
  dim3 ngrid((N + 255) / 256);

  // CSR build
  deg_kernel<<<egrid, blk, 0, stream>>>(dst, deg, E);
  scan_kernel<<<dim3(1), dim3(1024), 0, stream>>>(deg, rowptr, N, E);
  hipMemcpyAsync(cursor, rowptr, (size_t)N * 4, hipMemcpyDeviceToDevice, stream);
  scatter_kernel<<<egrid, blk, 0, stream>>>(src, dst, eattr, cursor, esrc, eea, E);

  // layer 1 (fused gather + MLP)
  node1_fused<<<ngrid, blk, 0, stream>>>(x, rowptr, esrc, eea, we1, be1, w11, b11, w12, b12, h1, N);

  // layer 2 (fused gather + MLP + readout), wave per node
  dim3 l2grid((N + 3) / 4);
  layer2_fused<<<l2grid, blk, 0, stream>>>(h1, rowptr, esrc, eea, we2, be2, w21, b21,
                                           w22, b22, wr1, br1, wr2, br2, raw, N);

  // segment softmax + scale
  segmax_kernel<<<ngrid, blk, 0, stream>>>(raw, batch, gmax, N);
  expsum_kernel<<<ngrid, blk, 0, stream>>>(raw, batch, gmax, z, gsum, N);
  final_kernel<<<ngrid, blk, 0, stream>>>(z, batch, gsum, Btot, (float*)d_out, N);
}

// Round 3
// 806.178 us; speedup vs baseline: 1.7570x; 1.4804x over previous
//
#include <hip/hip_runtime.h>

// ---------- float <-> order-preserving uint key (for atomicMax on floats) ----
__device__ __forceinline__ unsigned fkey(float f) {
  unsigned b = __float_as_uint(f);
  return (b & 0x80000000u) ? ~b : (b | 0x80000000u);
}
__device__ __forceinline__ float funkey(unsigned u) {
  unsigned b = (u & 0x80000000u) ? (u & 0x7FFFFFFFu) : ~u;
  return __uint_as_float(b);
}

// ---------- CSR build ---------------------------------------------------------
__global__ void deg_kernel(const int* __restrict__ dst, int* __restrict__ deg, int E) {
  int j = blockIdx.x * blockDim.x + threadIdx.x;
  if (j < E) atomicAdd(&deg[dst[j]], 1);
}

// single-block exclusive scan (N=100k, ~98 elems/thread)
__global__ void scan_kernel(const int* __restrict__ deg, int* __restrict__ rowptr, int N, int E) {
  __shared__ int partial[1024];
  int t = threadIdx.x;
  int per = (N + 1023) >> 10;
  int start = t * per, end = min(start + per, N);
  int sum = 0;
  for (int p = start; p < end; ++p) sum += deg[p];
  partial[t] = sum;
  __syncthreads();
  if (t == 0) {
    int run = 0;
    for (int i = 0; i < 1024; ++i) { int v = partial[i]; partial[i] = run; run += v; }
  }
  __syncthreads();
  int run = partial[t];
  for (int p = start; p < end; ++p) { rowptr[p] = run; run += deg[p]; }
  if (t == 0) rowptr[N] = E;
}

__global__ void scatter_kernel(const int* __restrict__ src, const int* __restrict__ dst,
                               const float* __restrict__ ea, int* __restrict__ cursor,
                               int* __restrict__ esrc, float* __restrict__ eea, int E) {
  int j = blockIdx.x * blockDim.x + threadIdx.x;
  if (j >= E) return;
  int d = dst[j];
  int pos = atomicAdd(&cursor[d], 1);
  esrc[pos] = src[j];
  eea[pos] = ea[j];
}

// ---------- Layer 1 fused: gather-agg + MLP (thread per node) ----------------
__global__ void node1_fused(const float* __restrict__ x, const int* __restrict__ rowptr,
                            const int* __restrict__ esrc, const float* __restrict__ eea,
                            const float* __restrict__ we1, const float* __restrict__ be1,
                            const float* __restrict__ w11, const float* __restrict__ b11,
                            const float* __restrict__ w12, const float* __restrict__ b12,
                            float* __restrict__ h1, int N) {
  __shared__ float sW1[9 * 64];
  __shared__ float sB1[64];
  __shared__ float sW2[64 * 64];
  __shared__ float sB2[64];
  for (int t = threadIdx.x; t < 9 * 64; t += blockDim.x) sW1[t] = w11[t];
  for (int t = threadIdx.x; t < 64; t += blockDim.x) { sB1[t] = b11[t]; sB2[t] = b12[t]; }
  for (int t = threadIdx.x; t < 64 * 64; t += blockDim.x) sW2[t] = w12[t];
  __syncthreads();
  int i = blockIdx.x * blockDim.x + threadIdx.x;
  if (i >= N) return;

  float we[9], be[9];
#pragma unroll
  for (int f = 0; f < 9; ++f) { we[f] = we1[f]; be[f] = be1[f]; }
  float acc[9];
#pragma unroll
  for (int f = 0; f < 9; ++f) acc[f] = 0.0f;

  int p0 = rowptr[i], p1 = rowptr[i + 1];
  int p = p0;
  // unroll by 2: two independent x-row gathers in flight
  for (; p + 1 < p1; p += 2) {
    int s0 = esrc[p], s1 = esrc[p + 1];
    float a0 = eea[p], a1 = eea[p + 1];
    float r0[9], r1[9];
#pragma unroll
    for (int f = 0; f < 9; ++f) r0[f] = x[(size_t)s0 * 9 + f];
#pragma unroll
    for (int f = 0; f < 9; ++f) r1[f] = x[(size_t)s1 * 9 + f];
#pragma unroll
    for (int f = 0; f < 9; ++f) {
      acc[f] += fmaxf(fmaf(a0, we[f], be[f]) + r0[f], 0.0f);
      acc[f] += fmaxf(fmaf(a1, we[f], be[f]) + r1[f], 0.0f);
    }
  }
  for (; p < p1; ++p) {
    int s = esrc[p];
    float a = eea[p];
#pragma unroll
    for (int f = 0; f < 9; ++f) {
      float m = fmaf(a, we[f], be[f]) + x[(size_t)s * 9 + f];
      acc[f] += fmaxf(m, 0.0f);
    }
  }
  float xin[9];
#pragma unroll
  for (int f = 0; f < 9; ++f) xin[f] = x[(size_t)i * 9 + f] + acc[f];

  float t1[64];
#pragma unroll
  for (int o = 0; o < 64; ++o) {
    float a = sB1[o];
#pragma unroll
    for (int k = 0; k < 9; ++k) a = fmaf(xin[k], sW1[k * 64 + o], a);
    t1[o] = fmaxf(a, 0.0f);
  }
  for (int o = 0; o < 64; ++o) {
    float a = sB2[o];
#pragma unroll
    for (int k = 0; k < 64; ++k) a = fmaf(t1[k], sW2[k * 64 + o], a);
    h1[(size_t)i * 64 + o] = fmaxf(a, 0.0f);
  }
}

// ---------- Layer 2 gather: wave-per-node, no LDS, unroll-4 ------------------
__global__ void __launch_bounds__(256, 8) gather2_kernel(
    const float* __restrict__ h1, const int* __restrict__ rowptr,
    const int* __restrict__ esrc, const float* __restrict__ eea,
    const float* __restrict__ we2, const float* __restrict__ be2,
    float* __restrict__ agg2, int N) {
  int wid = threadIdx.x >> 6;
  int lane = threadIdx.x & 63;
  int i = blockIdx.x * 4 + wid;
  if (i >= N) return;

  float we_l = we2[lane], be_l = be2[lane];
  float acc = 0.0f;
  int p0 = rowptr[i], p1 = rowptr[i + 1];
  int p = p0;
  // 4 independent 256B row gathers in flight
  for (; p + 3 < p1; p += 4) {
    int s0 = esrc[p], s1 = esrc[p + 1], s2 = esrc[p + 2], s3 = esrc[p + 3];
    float a0 = eea[p], a1 = eea[p + 1], a2 = eea[p + 2], a3 = eea[p + 3];
    float h0 = h1[(size_t)s0 * 64 + lane];
    float h1v = h1[(size_t)s1 * 64 + lane];
    float h2 = h1[(size_t)s2 * 64 + lane];
    float h3 = h1[(size_t)s3 * 64 + lane];
    acc += fmaxf(fmaf(a0, we_l, be_l) + h0, 0.0f);
    acc += fmaxf(fmaf(a1, we_l, be_l) + h1v, 0.0f);
    acc += fmaxf(fmaf(a2, we_l, be_l) + h2, 0.0f);
    acc += fmaxf(fmaf(a3, we_l, be_l) + h3, 0.0f);
  }
  for (; p < p1; ++p) {
    int s = esrc[p];
    float a = eea[p];
    acc += fmaxf(fmaf(a, we_l, be_l) + h1[(size_t)s * 64 + lane], 0.0f);
  }
  agg2[(size_t)i * 64 + lane] = acc;
}

// ---------- Layer 2 node MLP + readout: raw[i] (thread per node) -------------
__global__ void node2_kernel(const float* __restrict__ h1, const float* __restrict__ agg2,
                             const float* __restrict__ w21, const float* __restrict__ b21,
                             const float* __restrict__ w22, const float* __restrict__ b22,
                             const float* __restrict__ wr1, const float* __restrict__ br1,
                             const float* __restrict__ wr2, const float* __restrict__ br2,
                             float* __restrict__ raw, int N) {
  __shared__ float sW1[64 * 64];
  __shared__ float sB1[64];
  __shared__ float sW2[64 * 64];
  __shared__ float sB2[64];
  __shared__ float sWr1[64 * 32];
  __shared__ float sBr1[32];
  __shared__ float sWr2[32];
  __shared__ float sBr2;
  for (int t = threadIdx.x; t < 64 * 64; t += blockDim.x) { sW1[t] = w21[t]; sW2[t] = w22[t]; }
  for (int t = threadIdx.x; t < 64; t += blockDim.x) { sB1[t] = b21[t]; sB2[t] = b22[t]; }
  for (int t = threadIdx.x; t < 64 * 32; t += blockDim.x) sWr1[t] = wr1[t];
  for (int t = threadIdx.x; t < 32; t += blockDim.x) { sBr1[t] = br1[t]; sWr2[t] = wr2[t]; }
  if (threadIdx.x == 0) sBr2 = br2[0];
  __syncthreads();
  int i = blockIdx.x * blockDim.x + threadIdx.x;
  if (i >= N) return;
  float hin[64];
#pragma unroll
  for (int k = 0; k < 64; ++k) hin[k] = h1[(size_t)i * 64 + k] + agg2[(size_t)i * 64 + k];
  float a1[64];
  for (int o = 0; o < 64; ++o) {
    float acc = sB1[o];
#pragma unroll
    for (int k = 0; k < 64; ++k) acc = fmaf(hin[k], sW1[k * 64 + o], acc);
    a1[o] = fmaxf(acc, 0.0f);
  }
  float a2[64];
  for (int o = 0; o < 64; ++o) {
    float acc = sB2[o];
#pragma unroll
    for (int k = 0; k < 64; ++k) acc = fmaf(a1[k], sW2[k * 64 + o], acc);
    a2[o] = fmaxf(acc, 0.0f);
  }
  float r[32];
  for (int o = 0; o < 32; ++o) {
    float acc = sBr1[o];
#pragma unroll
    for (int k = 0; k < 64; ++k) acc = fmaf(a2[k], sWr1[k * 32 + o], acc);
    r[o] = fmaxf(acc, 0.0f);
  }
  float acc = sBr2;
#pragma unroll
  for (int k = 0; k < 32; ++k) acc = fmaf(r[k], sWr2[k], acc);
  raw[i] = acc;
}

// ---------- Segment softmax --------------------------------------------------
__global__ void segmax_kernel(const float* __restrict__ raw, const int* __restrict__ batch,
                              unsigned* __restrict__ gmax, int N) {
  int i = blockIdx.x * blockDim.x + threadIdx.x;
  if (i >= N) return;
  atomicMax(&gmax[batch[i]], fkey(raw[i]));
}

__global__ void expsum_kernel(const float* __restrict__ raw, const int* __restrict__ batch,
                              const unsigned* __restrict__ gmax, float* __restrict__ z,
                              float* __restrict__ gsum, int N) {
  int i = blockIdx.x * blockDim.x + threadIdx.x;
  if (i >= N) return;
  int b = batch[i];
  float zz = expf(raw[i] - funkey(gmax[b]));
  z[i] = zz;
  atomicAdd(&gsum[b], zz);
}

__global__ void final_kernel(const float* __restrict__ z, const int* __restrict__ batch,
                             const float* __restrict__ gsum, const float* __restrict__ Btot,
                             float* __restrict__ out, int N) {
  int i = blockIdx.x * blockDim.x + threadIdx.x;
  if (i >= N) return;
  int b = batch[i];
  out[i] = z[i] / gsum[b] * Btot[b];
}

extern "C" void kernel_launch(void* const* d_in, const int* in_sizes, int n_in,
                              void* d_out, int out_size, void* d_ws, size_t ws_size,
                              hipStream_t stream) {
  const float* x     = (const float*)d_in[0];
  const int* eidx    = (const int*)d_in[1];
  const float* eattr = (const float*)d_in[2];
  const int* batch   = (const int*)d_in[3];
  const float* Btot  = (const float*)d_in[4];
  const float* we1 = (const float*)d_in[5];
  const float* be1 = (const float*)d_in[6];
  const float* w11 = (const float*)d_in[7];
  const float* b11 = (const float*)d_in[8];
  const float* w12 = (const float*)d_in[9];
  const float* b12 = (const float*)d_in[10];
  const float* we2 = (const float*)d_in[11];
  const float* be2 = (const float*)d_in[12];
  const float* w21 = (const float*)d_in[13];
  const float* b21 = (const float*)d_in[14];
  const float* w22 = (const float*)d_in[15];
  const float* b22 = (const float*)d_in[16];
  const float* wr1 = (const float*)d_in[17];
  const float* br1 = (const float*)d_in[18];
  const float* wr2 = (const float*)d_in[19];
  const float* br2 = (const float*)d_in[20];

  const int N  = in_sizes[0] / 9;     // 100000
  const int E  = in_sizes[2];         // 1600000
  const int NG = in_sizes[4];         // 1000
  const int* src = eidx;
  const int* dst = eidx + E;

  // workspace layout (all 4-byte elems)
  char* w = (char*)d_ws;
  int*   deg    = (int*)w;                 w += (size_t)N * 4;
  int*   rowptr = (int*)w;                 w += (size_t)(N + 1) * 4;
  int*   cursor = (int*)w;                 w += (size_t)N * 4;
  int*   esrc   = (int*)w;                 w += (size_t)E * 4;
  float* eea    = (float*)w;               w += (size_t)E * 4;
  float* h1     = (float*)w;               w += (size_t)N * 64 * 4;
  float* agg2   = (float*)w;               w += (size_t)N * 64 * 4;
  float* raw    = (float*)w;               w += (size_t)N * 4;
  float* z      = (float*)w;               w += (size_t)N * 4;
  unsigned* gmax = (unsigned*)w;           w += (size_t)NG * 4;
  float* gsum   = (float*)w;               w += (size_t)NG * 4;

  hipMemsetAsync(deg, 0, (size_t)N * 4, stream);
  hipMemsetAsync(gmax, 0, (size_t)NG * 8, stream);  // gmax + gsum (contiguous)

  dim3 blk(256);
  dim3 egrid((E + 255) / 256);
  dim3 ngrid((N + 255) / 256);

  // CSR build
  deg_kernel<<<egrid, blk, 0, stream>>>(dst, deg, E);
  scan_kernel<<<dim3(1), dim3(1024), 0, stream>>>(deg, rowptr, N, E);
  hipMemcpyAsync(cursor, rowptr, (size_t)N * 4, hipMemcpyDeviceToDevice, stream);
  scatter_kernel<<<egrid, blk, 0, stream>>>(src, dst, eattr, cursor, esrc, eea, E);

  // layer 1 (fused gather + MLP)
  node1_fused<<<ngrid, blk, 0, stream>>>(x, rowptr, esrc, eea, we1, be1, w11, b11, w12, b12, h1, N);

  // layer 2: high-occupancy gather, then LDS-weight MLP
  dim3 l2grid((N + 3) / 4);
  gather2_kernel<<<l2grid, blk, 0, stream>>>(h1, rowptr, esrc, eea, we2, be2, agg2, N);
  node2_kernel<<<ngrid, blk, 0, stream>>>(h1, agg2, w21, b21, w22, b22,
                                          wr1, br1, wr2, br2, raw, N);

  // segment softmax + scale
  segmax_kernel<<<ngrid, blk, 0, stream>>>(raw, batch, gmax, N);
  expsum_kernel<<<ngrid, blk, 0, stream>>>(raw, batch, gmax, z, gsum, N);
  final_kernel<<<ngrid, blk, 0, stream>>>(z, batch, gsum, Btot, (float*)d_out, N);
}

// Round 4
// 742.197 us; speedup vs baseline: 1.9085x; 1.0862x over previous
//
#include <hip/hip_runtime.h>

// ---------- float <-> order-preserving uint key (for atomicMax on floats) ----
__device__ __forceinline__ unsigned fkey(float f) {
  unsigned b = __float_as_uint(f);
  return (b & 0x80000000u) ? ~b : (b | 0x80000000u);
}
__device__ __forceinline__ float funkey(unsigned u) {
  unsigned b = (u & 0x80000000u) ? (u & 0x7FFFFFFFu) : ~u;
  return __uint_as_float(b);
}

// ---------- CSR build ---------------------------------------------------------
__global__ void deg_kernel(const int* __restrict__ dst, int* __restrict__ deg, int E) {
  int j = blockIdx.x * blockDim.x + threadIdx.x;
  if (j < E) atomicAdd(&deg[dst[j]], 1);
}

// single-block exclusive scan (N=100k, ~98 elems/thread)
__global__ void scan_kernel(const int* __restrict__ deg, int* __restrict__ rowptr, int N, int E) {
  __shared__ int partial[1024];
  int t = threadIdx.x;
  int per = (N + 1023) >> 10;
  int start = t * per, end = min(start + per, N);
  int sum = 0;
  for (int p = start; p < end; ++p) sum += deg[p];
  partial[t] = sum;
  __syncthreads();
  if (t == 0) {
    int run = 0;
    for (int i = 0; i < 1024; ++i) { int v = partial[i]; partial[i] = run; run += v; }
  }
  __syncthreads();
  int run = partial[t];
  for (int p = start; p < end; ++p) { rowptr[p] = run; run += deg[p]; }
  if (t == 0) rowptr[N] = E;
}

__global__ void scatter_kernel(const int* __restrict__ src, const int* __restrict__ dst,
                               const float* __restrict__ ea, int* __restrict__ cursor,
                               int* __restrict__ esrc, float* __restrict__ eea, int E) {
  int j = blockIdx.x * blockDim.x + threadIdx.x;
  if (j >= E) return;
  int d = dst[j];
  int pos = atomicAdd(&cursor[d], 1);
  esrc[pos] = src[j];
  eea[pos] = ea[j];
}

// ---------- Layer 1 fused: gather-agg + MLP (thread per node) ----------------
// __launch_bounds__(256,4): VGPR cap 128 so t1[64]+acc[9]+r0/r1 stay in regs.
__global__ void __launch_bounds__(256, 4) node1_fused(
    const float* __restrict__ x, const int* __restrict__ rowptr,
    const int* __restrict__ esrc, const float* __restrict__ eea,
    const float* __restrict__ we1, const float* __restrict__ be1,
    const float* __restrict__ w11, const float* __restrict__ b11,
    const float* __restrict__ w12, const float* __restrict__ b12,
    float* __restrict__ h1, int N) {
  __shared__ float sW1[9 * 64];
  __shared__ float sB1[64];
  __shared__ float sW2[64 * 64];
  __shared__ float sB2[64];
  for (int t = threadIdx.x; t < 9 * 64; t += blockDim.x) sW1[t] = w11[t];
  for (int t = threadIdx.x; t < 64; t += blockDim.x) { sB1[t] = b11[t]; sB2[t] = b12[t]; }
  for (int t = threadIdx.x; t < 64 * 64; t += blockDim.x) sW2[t] = w12[t];
  __syncthreads();
  int i = blockIdx.x * blockDim.x + threadIdx.x;
  if (i >= N) return;

  float we[9], be[9];
#pragma unroll
  for (int f = 0; f < 9; ++f) { we[f] = we1[f]; be[f] = be1[f]; }
  float acc[9];
#pragma unroll
  for (int f = 0; f < 9; ++f) acc[f] = 0.0f;

  int p0 = rowptr[i], p1 = rowptr[i + 1];
  int p = p0;
  for (; p + 1 < p1; p += 2) {
    int s0 = esrc[p], s1 = esrc[p + 1];
    float a0 = eea[p], a1 = eea[p + 1];
    float r0[9], r1[9];
#pragma unroll
    for (int f = 0; f < 9; ++f) r0[f] = x[(size_t)s0 * 9 + f];
#pragma unroll
    for (int f = 0; f < 9; ++f) r1[f] = x[(size_t)s1 * 9 + f];
#pragma unroll
    for (int f = 0; f < 9; ++f) {
      acc[f] += fmaxf(fmaf(a0, we[f], be[f]) + r0[f], 0.0f);
      acc[f] += fmaxf(fmaf(a1, we[f], be[f]) + r1[f], 0.0f);
    }
  }
  for (; p < p1; ++p) {
    int s = esrc[p];
    float a = eea[p];
#pragma unroll
    for (int f = 0; f < 9; ++f) {
      float m = fmaf(a, we[f], be[f]) + x[(size_t)s * 9 + f];
      acc[f] += fmaxf(m, 0.0f);
    }
  }
  float xin[9];
#pragma unroll
  for (int f = 0; f < 9; ++f) xin[f] = x[(size_t)i * 9 + f] + acc[f];

  float t1[64];
#pragma unroll
  for (int o = 0; o < 64; ++o) {
    float a = sB1[o];
#pragma unroll
    for (int k = 0; k < 9; ++k) a = fmaf(xin[k], sW1[k * 64 + o], a);
    t1[o] = fmaxf(a, 0.0f);
  }
  for (int o = 0; o < 64; ++o) {
    float a = sB2[o];
#pragma unroll
    for (int k = 0; k < 64; ++k) a = fmaf(t1[k], sW2[k * 64 + o], a);
    h1[(size_t)i * 64 + o] = fmaxf(a, 0.0f);
  }
}

// ---------- Layer 2 gather: wave-per-node, no LDS, unroll-4 ------------------
__global__ void __launch_bounds__(256, 8) gather2_kernel(
    const float* __restrict__ h1, const int* __restrict__ rowptr,
    const int* __restrict__ esrc, const float* __restrict__ eea,
    const float* __restrict__ we2, const float* __restrict__ be2,
    float* __restrict__ agg2, int N) {
  int wid = threadIdx.x >> 6;
  int lane = threadIdx.x & 63;
  int i = blockIdx.x * 4 + wid;
  if (i >= N) return;

  float we_l = we2[lane], be_l = be2[lane];
  float acc = 0.0f;
  int p0 = rowptr[i], p1 = rowptr[i + 1];
  int p = p0;
  for (; p + 3 < p1; p += 4) {
    int s0 = esrc[p], s1 = esrc[p + 1], s2 = esrc[p + 2], s3 = esrc[p + 3];
    float a0 = eea[p], a1 = eea[p + 1], a2 = eea[p + 2], a3 = eea[p + 3];
    float h0 = h1[(size_t)s0 * 64 + lane];
    float h1v = h1[(size_t)s1 * 64 + lane];
    float h2 = h1[(size_t)s2 * 64 + lane];
    float h3 = h1[(size_t)s3 * 64 + lane];
    acc += fmaxf(fmaf(a0, we_l, be_l) + h0, 0.0f);
    acc += fmaxf(fmaf(a1, we_l, be_l) + h1v, 0.0f);
    acc += fmaxf(fmaf(a2, we_l, be_l) + h2, 0.0f);
    acc += fmaxf(fmaf(a3, we_l, be_l) + h3, 0.0f);
  }
  for (; p < p1; ++p) {
    int s = esrc[p];
    float a = eea[p];
    acc += fmaxf(fmaf(a, we_l, be_l) + h1[(size_t)s * 64 + lane], 0.0f);
  }
  agg2[(size_t)i * 64 + lane] = acc;
}

// ---------- Layer 2 node MLP + readout: raw[i] (thread per node) -------------
// __launch_bounds__(256,3): VGPR cap ~170 — hin/a1/a2/r live in registers,
// no scratch spill (R3: VGPR=64 forced 62MB of spill traffic).
__global__ void __launch_bounds__(256, 3) node2_kernel(
    const float* __restrict__ h1, const float* __restrict__ agg2,
    const float* __restrict__ w21, const float* __restrict__ b21,
    const float* __restrict__ w22, const float* __restrict__ b22,
    const float* __restrict__ wr1, const float* __restrict__ br1,
    const float* __restrict__ wr2, const float* __restrict__ br2,
    float* __restrict__ raw, int N) {
  __shared__ float sW1[64 * 64];
  __shared__ float sB1[64];
  __shared__ float sW2[64 * 64];
  __shared__ float sB2[64];
  __shared__ float sWr1[64 * 32];
  __shared__ float sBr1[32];
  __shared__ float sWr2[32];
  __shared__ float sBr2;
  for (int t = threadIdx.x; t < 64 * 64; t += blockDim.x) { sW1[t] = w21[t]; sW2[t] = w22[t]; }
  for (int t = threadIdx.x; t < 64; t += blockDim.x) { sB1[t] = b21[t]; sB2[t] = b22[t]; }
  for (int t = threadIdx.x; t < 64 * 32; t += blockDim.x) sWr1[t] = wr1[t];
  for (int t = threadIdx.x; t < 32; t += blockDim.x) { sBr1[t] = br1[t]; sWr2[t] = wr2[t]; }
  if (threadIdx.x == 0) sBr2 = br2[0];
  __syncthreads();
  int i = blockIdx.x * blockDim.x + threadIdx.x;
  if (i >= N) return;
  float hin[64];
#pragma unroll
  for (int k = 0; k < 64; ++k) hin[k] = h1[(size_t)i * 64 + k] + agg2[(size_t)i * 64 + k];
  float a1[64];
  for (int o = 0; o < 64; ++o) {
    float acc = sB1[o];
#pragma unroll
    for (int k = 0; k < 64; ++k) acc = fmaf(hin[k], sW1[k * 64 + o], acc);
    a1[o] = fmaxf(acc, 0.0f);
  }
  // overwrite hin with a2 to limit peak register pressure
  float a2[64];
  for (int o = 0; o < 64; ++o) {
    float acc = sB2[o];
#pragma unroll
    for (int k = 0; k < 64; ++k) acc = fmaf(a1[k], sW2[k * 64 + o], acc);
    a2[o] = fmaxf(acc, 0.0f);
  }
  float r[32];
  for (int o = 0; o < 32; ++o) {
    float acc = sBr1[o];
#pragma unroll
    for (int k = 0; k < 64; ++k) acc = fmaf(a2[k], sWr1[k * 32 + o], acc);
    r[o] = fmaxf(acc, 0.0f);
  }
  float acc = sBr2;
#pragma unroll
  for (int k = 0; k < 32; ++k) acc = fmaf(r[k], sWr2[k], acc);
  raw[i] = acc;
}

// ---------- Segment softmax --------------------------------------------------
__global__ void segmax_kernel(const float* __restrict__ raw, const int* __restrict__ batch,
                              unsigned* __restrict__ gmax, int N) {
  int i = blockIdx.x * blockDim.x + threadIdx.x;
  if (i >= N) return;
  atomicMax(&gmax[batch[i]], fkey(raw[i]));
}

__global__ void expsum_kernel(const float* __restrict__ raw, const int* __restrict__ batch,
                              const unsigned* __restrict__ gmax, float* __restrict__ z,
                              float* __restrict__ gsum, int N) {
  int i = blockIdx.x * blockDim.x + threadIdx.x;
  if (i >= N) return;
  int b = batch[i];
  float zz = expf(raw[i] - funkey(gmax[b]));
  z[i] = zz;
  atomicAdd(&gsum[b], zz);
}

__global__ void final_kernel(const float* __restrict__ z, const int* __restrict__ batch,
                             const float* __restrict__ gsum, const float* __restrict__ Btot,
                             float* __restrict__ out, int N) {
  int i = blockIdx.x * blockDim.x + threadIdx.x;
  if (i >= N) return;
  int b = batch[i];
  out[i] = z[i] / gsum[b] * Btot[b];
}

extern "C" void kernel_launch(void* const* d_in, const int* in_sizes, int n_in,
                              void* d_out, int out_size, void* d_ws, size_t ws_size,
                              hipStream_t stream) {
  const float* x     = (const float*)d_in[0];
  const int* eidx    = (const int*)d_in[1];
  const float* eattr = (const float*)d_in[2];
  const int* batch   = (const int*)d_in[3];
  const float* Btot  = (const float*)d_in[4];
  const float* we1 = (const float*)d_in[5];
  const float* be1 = (const float*)d_in[6];
  const float* w11 = (const float*)d_in[7];
  const float* b11 = (const float*)d_in[8];
  const float* w12 = (const float*)d_in[9];
  const float* b12 = (const float*)d_in[10];
  const float* we2 = (const float*)d_in[11];
  const float* be2 = (const float*)d_in[12];
  const float* w21 = (const float*)d_in[13];
  const float* b21 = (const float*)d_in[14];
  const float* w22 = (const float*)d_in[15];
  const float* b22 = (const float*)d_in[16];
  const float* wr1 = (const float*)d_in[17];
  const float* br1 = (const float*)d_in[18];
  const float* wr2 = (const float*)d_in[19];
  const float* br2 = (const float*)d_in[20];

  const int N  = in_sizes[0] / 9;     // 100000
  const int E  = in_sizes[2];         // 1600000
  const int NG = in_sizes[4];         // 1000
  const int* src = eidx;
  const int* dst = eidx + E;

  // workspace layout (all 4-byte elems)
  char* w = (char*)d_ws;
  int*   deg    = (int*)w;                 w += (size_t)N * 4;
  int*   rowptr = (int*)w;                 w += (size_t)(N + 1) * 4;
  int*   cursor = (int*)w;                 w += (size_t)N * 4;
  int*   esrc   = (int*)w;                 w += (size_t)E * 4;
  float* eea    = (float*)w;               w += (size_t)E * 4;
  float* h1     = (float*)w;               w += (size_t)N * 64 * 4;
  float* agg2   = (float*)w;               w += (size_t)N * 64 * 4;
  float* raw    = (float*)w;               w += (size_t)N * 4;
  float* z      = (float*)w;               w += (size_t)N * 4;
  unsigned* gmax = (unsigned*)w;           w += (size_t)NG * 4;
  float* gsum   = (float*)w;               w += (size_t)NG * 4;

  hipMemsetAsync(deg, 0, (size_t)N * 4, stream);
  hipMemsetAsync(gmax, 0, (size_t)NG * 8, stream);  // gmax + gsum (contiguous)

  dim3 blk(256);
  dim3 egrid((E + 255) / 256);
  dim3 ngrid((N + 255) / 256);

  // CSR build
  deg_kernel<<<egrid, blk, 0, stream>>>(dst, deg, E);
  scan_kernel<<<dim3(1), dim3(1024), 0, stream>>>(deg, rowptr, N, E);
  hipMemcpyAsync(cursor, rowptr, (size_t)N * 4, hipMemcpyDeviceToDevice, stream);
  scatter_kernel<<<egrid, blk, 0, stream>>>(src, dst, eattr, cursor, esrc, eea, E);

  // layer 1 (fused gather + MLP)
  node1_fused<<<ngrid, blk, 0, stream>>>(x, rowptr, esrc, eea, we1, be1, w11, b11, w12, b12, h1, N);

  // layer 2: high-occupancy gather, then LDS-weight MLP
  dim3 l2grid((N + 3) / 4);
  gather2_kernel<<<l2grid, blk, 0, stream>>>(h1, rowptr, esrc, eea, we2, be2, agg2, N);
  node2_kernel<<<ngrid, blk, 0, stream>>>(h1, agg2, w21, b21, w22, b22,
                                          wr1, br1, wr2, br2, raw, N);

  // segment softmax + scale
  segmax_kernel<<<ngrid, blk, 0, stream>>>(raw, batch, gmax, N);
  expsum_kernel<<<ngrid, blk, 0, stream>>>(raw, batch, gmax, z, gsum, N);
  final_kernel<<<ngrid, blk, 0, stream>>>(z, batch, gsum, Btot, (float*)d_out, N);
}

// Round 5
// 582.519 us; speedup vs baseline: 2.4317x; 1.2741x over previous
//
#include <hip/hip_runtime.h>

// ---------- float <-> order-preserving uint key (for atomicMax on floats) ----
__device__ __forceinline__ unsigned fkey(float f) {
  unsigned b = __float_as_uint(f);
  return (b & 0x80000000u) ? ~b : (b | 0x80000000u);
}
__device__ __forceinline__ float funkey(unsigned u) {
  unsigned b = (u & 0x80000000u) ? (u & 0x7FFFFFFFu) : ~u;
  return __uint_as_float(b);
}

// ---------- CSR build ---------------------------------------------------------
__global__ void deg_kernel(const int* __restrict__ dst, int* __restrict__ deg, int E) {
  int j = blockIdx.x * blockDim.x + threadIdx.x;
  if (j < E) atomicAdd(&deg[dst[j]], 1);
}

// ---- hierarchical exclusive scan over deg[N] (3 passes, all parallel) -------
__global__ void scan_pass1(const int* __restrict__ deg, int* __restrict__ blocksum, int N) {
  __shared__ int sdata[1024];
  int i = blockIdx.x * 1024 + threadIdx.x;
  sdata[threadIdx.x] = (i < N) ? deg[i] : 0;
  __syncthreads();
  for (int s = 512; s > 0; s >>= 1) {
    if (threadIdx.x < s) sdata[threadIdx.x] += sdata[threadIdx.x + s];
    __syncthreads();
  }
  if (threadIdx.x == 0) blocksum[blockIdx.x] = sdata[0];
}

__global__ void scan_pass2(int* __restrict__ blocksum, int nb) {
  __shared__ int sdata[1024];
  int t = threadIdx.x;
  sdata[t] = (t < nb) ? blocksum[t] : 0;
  __syncthreads();
  if (t == 0) {
    int run = 0;
    for (int i = 0; i < nb; ++i) { int v = sdata[i]; sdata[i] = run; run += v; }
  }
  __syncthreads();
  if (t < nb) blocksum[t] = sdata[t];
}

__global__ void scan_pass3(const int* __restrict__ deg, const int* __restrict__ blocksum,
                           int* __restrict__ rowptr, int* __restrict__ cursor, int N, int E) {
  __shared__ int sdata[1024];
  int i = blockIdx.x * 1024 + threadIdx.x;
  int v = (i < N) ? deg[i] : 0;
  sdata[threadIdx.x] = v;
  __syncthreads();
  // Hillis-Steele inclusive scan over 1024 elems
  for (int off = 1; off < 1024; off <<= 1) {
    int t = (threadIdx.x >= off) ? sdata[threadIdx.x - off] : 0;
    __syncthreads();
    sdata[threadIdx.x] += t;
    __syncthreads();
  }
  if (i < N) {
    int r = blocksum[blockIdx.x] + sdata[threadIdx.x] - v;  // exclusive
    rowptr[i] = r;
    cursor[i] = r;
  }
  if (i == 0) rowptr[N] = E;
}

__global__ void scatter_kernel(const int* __restrict__ src, const int* __restrict__ dst,
                               const float* __restrict__ ea, int* __restrict__ cursor,
                               int* __restrict__ esrc, float* __restrict__ eea, int E) {
  int j = blockIdx.x * blockDim.x + threadIdx.x;
  if (j >= E) return;
  int d = dst[j];
  int pos = atomicAdd(&cursor[d], 1);
  esrc[pos] = src[j];
  eea[pos] = ea[j];
}

// ---------- Layer 1 fused: gather-agg + MLP (thread per node) ----------------
__global__ void __launch_bounds__(256, 4) node1_fused(
    const float* __restrict__ x, const int* __restrict__ rowptr,
    const int* __restrict__ esrc, const float* __restrict__ eea,
    const float* __restrict__ we1, const float* __restrict__ be1,
    const float* __restrict__ w11, const float* __restrict__ b11,
    const float* __restrict__ w12, const float* __restrict__ b12,
    float* __restrict__ h1, int N) {
  __shared__ float sW1[9 * 64];
  __shared__ float sB1[64];
  __shared__ float sW2[64 * 64];
  __shared__ float sB2[64];
  for (int t = threadIdx.x; t < 9 * 64; t += blockDim.x) sW1[t] = w11[t];
  for (int t = threadIdx.x; t < 64; t += blockDim.x) { sB1[t] = b11[t]; sB2[t] = b12[t]; }
  for (int t = threadIdx.x; t < 64 * 64; t += blockDim.x) sW2[t] = w12[t];
  __syncthreads();
  int i = blockIdx.x * blockDim.x + threadIdx.x;
  if (i >= N) return;

  float we[9], be[9];
#pragma unroll
  for (int f = 0; f < 9; ++f) { we[f] = we1[f]; be[f] = be1[f]; }
  float acc[9];
#pragma unroll
  for (int f = 0; f < 9; ++f) acc[f] = 0.0f;

  int p0 = rowptr[i], p1 = rowptr[i + 1];
  int p = p0;
  for (; p + 1 < p1; p += 2) {
    int s0 = esrc[p], s1 = esrc[p + 1];
    float a0 = eea[p], a1 = eea[p + 1];
    float r0[9], r1[9];
#pragma unroll
    for (int f = 0; f < 9; ++f) r0[f] = x[(size_t)s0 * 9 + f];
#pragma unroll
    for (int f = 0; f < 9; ++f) r1[f] = x[(size_t)s1 * 9 + f];
#pragma unroll
    for (int f = 0; f < 9; ++f) {
      acc[f] += fmaxf(fmaf(a0, we[f], be[f]) + r0[f], 0.0f);
      acc[f] += fmaxf(fmaf(a1, we[f], be[f]) + r1[f], 0.0f);
    }
  }
  for (; p < p1; ++p) {
    int s = esrc[p];
    float a = eea[p];
#pragma unroll
    for (int f = 0; f < 9; ++f) {
      float m = fmaf(a, we[f], be[f]) + x[(size_t)s * 9 + f];
      acc[f] += fmaxf(m, 0.0f);
    }
  }
  float xin[9];
#pragma unroll
  for (int f = 0; f < 9; ++f) xin[f] = x[(size_t)i * 9 + f] + acc[f];

  float t1[64];
#pragma unroll
  for (int o = 0; o < 64; ++o) {
    float a = sB1[o];
#pragma unroll
    for (int k = 0; k < 9; ++k) a = fmaf(xin[k], sW1[k * 64 + o], a);
    t1[o] = fmaxf(a, 0.0f);
  }
  for (int o = 0; o < 64; ++o) {
    float a = sB2[o];
#pragma unroll
    for (int k = 0; k < 64; ++k) a = fmaf(t1[k], sW2[k * 64 + o], a);
    h1[(size_t)i * 64 + o] = fmaxf(a, 0.0f);
  }
}

// ---------- Layer 2 gather: wave-per-node, no LDS, unroll-4 ------------------
__global__ void __launch_bounds__(256, 8) gather2_kernel(
    const float* __restrict__ h1, const int* __restrict__ rowptr,
    const int* __restrict__ esrc, const float* __restrict__ eea,
    const float* __restrict__ we2, const float* __restrict__ be2,
    float* __restrict__ agg2, int N) {
  int wid = threadIdx.x >> 6;
  int lane = threadIdx.x & 63;
  int i = blockIdx.x * 4 + wid;
  if (i >= N) return;

  float we_l = we2[lane], be_l = be2[lane];
  float acc = 0.0f;
  int p0 = rowptr[i], p1 = rowptr[i + 1];
  int p = p0;
  for (; p + 3 < p1; p += 4) {
    int s0 = esrc[p], s1 = esrc[p + 1], s2 = esrc[p + 2], s3 = esrc[p + 3];
    float a0 = eea[p], a1 = eea[p + 1], a2 = eea[p + 2], a3 = eea[p + 3];
    float h0 = h1[(size_t)s0 * 64 + lane];
    float h1v = h1[(size_t)s1 * 64 + lane];
    float h2 = h1[(size_t)s2 * 64 + lane];
    float h3 = h1[(size_t)s3 * 64 + lane];
    acc += fmaxf(fmaf(a0, we_l, be_l) + h0, 0.0f);
    acc += fmaxf(fmaf(a1, we_l, be_l) + h1v, 0.0f);
    acc += fmaxf(fmaf(a2, we_l, be_l) + h2, 0.0f);
    acc += fmaxf(fmaf(a3, we_l, be_l) + h3, 0.0f);
  }
  for (; p < p1; ++p) {
    int s = esrc[p];
    float a = eea[p];
    acc += fmaxf(fmaf(a, we_l, be_l) + h1[(size_t)s * 64 + lane], 0.0f);
  }
  agg2[(size_t)i * 64 + lane] = acc;
}

// ---------- Layer 2 node MLP + readout: raw[i] (thread per node) -------------
__global__ void __launch_bounds__(256, 3) node2_kernel(
    const float* __restrict__ h1, const float* __restrict__ agg2,
    const float* __restrict__ w21, const float* __restrict__ b21,
    const float* __restrict__ w22, const float* __restrict__ b22,
    const float* __restrict__ wr1, const float* __restrict__ br1,
    const float* __restrict__ wr2, const float* __restrict__ br2,
    float* __restrict__ raw, int N) {
  __shared__ float sW1[64 * 64];
  __shared__ float sB1[64];
  __shared__ float sW2[64 * 64];
  __shared__ float sB2[64];
  __shared__ float sWr1[64 * 32];
  __shared__ float sBr1[32];
  __shared__ float sWr2[32];
  __shared__ float sBr2;
  for (int t = threadIdx.x; t < 64 * 64; t += blockDim.x) { sW1[t] = w21[t]; sW2[t] = w22[t]; }
  for (int t = threadIdx.x; t < 64; t += blockDim.x) { sB1[t] = b21[t]; sB2[t] = b22[t]; }
  for (int t = threadIdx.x; t < 64 * 32; t += blockDim.x) sWr1[t] = wr1[t];
  for (int t = threadIdx.x; t < 32; t += blockDim.x) { sBr1[t] = br1[t]; sWr2[t] = wr2[t]; }
  if (threadIdx.x == 0) sBr2 = br2[0];
  __syncthreads();
  int i = blockIdx.x * blockDim.x + threadIdx.x;
  if (i >= N) return;
  float hin[64];
#pragma unroll
  for (int k = 0; k < 64; ++k) hin[k] = h1[(size_t)i * 64 + k] + agg2[(size_t)i * 64 + k];
  float a1[64];
  for (int o = 0; o < 64; ++o) {
    float acc = sB1[o];
#pragma unroll
    for (int k = 0; k < 64; ++k) acc = fmaf(hin[k], sW1[k * 64 + o], acc);
    a1[o] = fmaxf(acc, 0.0f);
  }
  float a2[64];
  for (int o = 0; o < 64; ++o) {
    float acc = sB2[o];
#pragma unroll
    for (int k = 0; k < 64; ++k) acc = fmaf(a1[k], sW2[k * 64 + o], acc);
    a2[o] = fmaxf(acc, 0.0f);
  }
  float r[32];
  for (int o = 0; o < 32; ++o) {
    float acc = sBr1[o];
#pragma unroll
    for (int k = 0; k < 64; ++k) acc = fmaf(a2[k], sWr1[k * 32 + o], acc);
    r[o] = fmaxf(acc, 0.0f);
  }
  float acc = sBr2;
#pragma unroll
  for (int k = 0; k < 32; ++k) acc = fmaf(r[k], sWr2[k], acc);
  raw[i] = acc;
}

// ---------- Segment softmax --------------------------------------------------
__global__ void segmax_kernel(const float* __restrict__ raw, const int* __restrict__ batch,
                              unsigned* __restrict__ gmax, int N) {
  int i = blockIdx.x * blockDim.x + threadIdx.x;
  if (i >= N) return;
  atomicMax(&gmax[batch[i]], fkey(raw[i]));
}

__global__ void expsum_kernel(const float* __restrict__ raw, const int* __restrict__ batch,
                              const unsigned* __restrict__ gmax, float* __restrict__ z,
                              float* __restrict__ gsum, int N) {
  int i = blockIdx.x * blockDim.x + threadIdx.x;
  if (i >= N) return;
  int b = batch[i];
  float zz = expf(raw[i] - funkey(gmax[b]));
  z[i] = zz;
  atomicAdd(&gsum[b], zz);
}

__global__ void final_kernel(const float* __restrict__ z, const int* __restrict__ batch,
                             const float* __restrict__ gsum, const float* __restrict__ Btot,
                             float* __restrict__ out, int N) {
  int i = blockIdx.x * blockDim.x + threadIdx.x;
  if (i >= N) return;
  int b = batch[i];
  out[i] = z[i] / gsum[b] * Btot[b];
}

extern "C" void kernel_launch(void* const* d_in, const int* in_sizes, int n_in,
                              void* d_out, int out_size, void* d_ws, size_t ws_size,
                              hipStream_t stream) {
  const float* x     = (const float*)d_in[0];
  const int* eidx    = (const int*)d_in[1];
  const float* eattr = (const float*)d_in[2];
  const int* batch   = (const int*)d_in[3];
  const float* Btot  = (const float*)d_in[4];
  const float* we1 = (const float*)d_in[5];
  const float* be1 = (const float*)d_in[6];
  const float* w11 = (const float*)d_in[7];
  const float* b11 = (const float*)d_in[8];
  const float* w12 = (const float*)d_in[9];
  const float* b12 = (const float*)d_in[10];
  const float* we2 = (const float*)d_in[11];
  const float* be2 = (const float*)d_in[12];
  const float* w21 = (const float*)d_in[13];
  const float* b21 = (const float*)d_in[14];
  const float* w22 = (const float*)d_in[15];
  const float* b22 = (const float*)d_in[16];
  const float* wr1 = (const float*)d_in[17];
  const float* br1 = (const float*)d_in[18];
  const float* wr2 = (const float*)d_in[19];
  const float* br2 = (const float*)d_in[20];

  const int N  = in_sizes[0] / 9;     // 100000
  const int E  = in_sizes[2];         // 1600000
  const int NG = in_sizes[4];         // 1000
  const int* src = eidx;
  const int* dst = eidx + E;

  const int NB = (N + 1023) / 1024;   // scan blocks (98)

  // workspace layout (all 4-byte elems)
  char* w = (char*)d_ws;
  int*   deg    = (int*)w;                 w += (size_t)N * 4;
  int*   rowptr = (int*)w;                 w += (size_t)(N + 1) * 4;
  int*   cursor = (int*)w;                 w += (size_t)N * 4;
  int*   blocksum = (int*)w;               w += (size_t)1024 * 4;
  int*   esrc   = (int*)w;                 w += (size_t)E * 4;
  float* eea    = (float*)w;               w += (size_t)E * 4;
  float* h1     = (float*)w;               w += (size_t)N * 64 * 4;
  float* agg2   = (float*)w;               w += (size_t)N * 64 * 4;
  float* raw    = (float*)w;               w += (size_t)N * 4;
  float* z      = (float*)w;               w += (size_t)N * 4;
  unsigned* gmax = (unsigned*)w;           w += (size_t)NG * 4;
  float* gsum   = (float*)w;               w += (size_t)NG * 4;

  hipMemsetAsync(deg, 0, (size_t)N * 4, stream);
  hipMemsetAsync(gmax, 0, (size_t)NG * 8, stream);  // gmax + gsum (contiguous)

  dim3 blk(256);
  dim3 egrid((E + 255) / 256);
  dim3 ngrid((N + 255) / 256);

  // CSR build (parallel 3-pass scan; pass3 also fills cursor)
  deg_kernel<<<egrid, blk, 0, stream>>>(dst, deg, E);
  scan_pass1<<<dim3(NB), dim3(1024), 0, stream>>>(deg, blocksum, N);
  scan_pass2<<<dim3(1), dim3(1024), 0, stream>>>(blocksum, NB);
  scan_pass3<<<dim3(NB), dim3(1024), 0, stream>>>(deg, blocksum, rowptr, cursor, N, E);
  scatter_kernel<<<egrid, blk, 0, stream>>>(src, dst, eattr, cursor, esrc, eea, E);

  // layer 1 (fused gather + MLP)
  node1_fused<<<ngrid, blk, 0, stream>>>(x, rowptr, esrc, eea, we1, be1, w11, b11, w12, b12, h1, N);

  // layer 2: high-occupancy gather, then LDS-weight MLP
  dim3 l2grid((N + 3) / 4);
  gather2_kernel<<<l2grid, blk, 0, stream>>>(h1, rowptr, esrc, eea, we2, be2, agg2, N);
  node2_kernel<<<ngrid, blk, 0, stream>>>(h1, agg2, w21, b21, w22, b22,
                                          wr1, br1, wr2, br2, raw, N);

  // segment softmax + scale
  segmax_kernel<<<ngrid, blk, 0, stream>>>(raw, batch, gmax, N);
  expsum_kernel<<<ngrid, blk, 0, stream>>>(raw, batch, gmax, z, gsum, N);
  final_kernel<<<ngrid, blk, 0, stream>>>(z, batch, gsum, Btot, (float*)d_out, N);
}

// Round 6
// 549.440 us; speedup vs baseline: 2.5781x; 1.0602x over previous
//
#include <hip/hip_runtime.h>

// ---------- float <-> order-preserving uint key (for atomicMax on floats) ----
__device__ __forceinline__ unsigned fkey(float f) {
  unsigned b = __float_as_uint(f);
  return (b & 0x80000000u) ? ~b : (b | 0x80000000u);
}
__device__ __forceinline__ float funkey(unsigned u) {
  unsigned b = (u & 0x80000000u) ? (u & 0x7FFFFFFFu) : ~u;
  return __uint_as_float(b);
}

// ---------- CSR build ---------------------------------------------------------
__global__ void deg_kernel(const int* __restrict__ dst, int* __restrict__ deg, int E) {
  int j = blockIdx.x * blockDim.x + threadIdx.x;
  if (j < E) atomicAdd(&deg[dst[j]], 1);
}

// ---- hierarchical exclusive scan over deg[N] (3 passes, all parallel) -------
__global__ void scan_pass1(const int* __restrict__ deg, int* __restrict__ blocksum, int N) {
  __shared__ int sdata[1024];
  int i = blockIdx.x * 1024 + threadIdx.x;
  sdata[threadIdx.x] = (i < N) ? deg[i] : 0;
  __syncthreads();
  for (int s = 512; s > 0; s >>= 1) {
    if (threadIdx.x < s) sdata[threadIdx.x] += sdata[threadIdx.x + s];
    __syncthreads();
  }
  if (threadIdx.x == 0) blocksum[blockIdx.x] = sdata[0];
}

__global__ void scan_pass2(int* __restrict__ blocksum, int nb) {
  __shared__ int sdata[1024];
  int t = threadIdx.x;
  sdata[t] = (t < nb) ? blocksum[t] : 0;
  __syncthreads();
  if (t == 0) {
    int run = 0;
    for (int i = 0; i < nb; ++i) { int v = sdata[i]; sdata[i] = run; run += v; }
  }
  __syncthreads();
  if (t < nb) blocksum[t] = sdata[t];
}

__global__ void scan_pass3(const int* __restrict__ deg, const int* __restrict__ blocksum,
                           int* __restrict__ rowptr, int* __restrict__ cursor, int N, int E) {
  __shared__ int sdata[1024];
  int i = blockIdx.x * 1024 + threadIdx.x;
  int v = (i < N) ? deg[i] : 0;
  sdata[threadIdx.x] = v;
  __syncthreads();
  for (int off = 1; off < 1024; off <<= 1) {
    int t = (threadIdx.x >= off) ? sdata[threadIdx.x - off] : 0;
    __syncthreads();
    sdata[threadIdx.x] += t;
    __syncthreads();
  }
  if (i < N) {
    int r = blocksum[blockIdx.x] + sdata[threadIdx.x] - v;  // exclusive
    rowptr[i] = r;
    cursor[i] = r;
  }
  if (i == 0) rowptr[N] = E;
}

// single 8B store per edge: {src, ea-bits} — halves dirtied write sectors
__global__ void scatter_kernel(const int* __restrict__ src, const int* __restrict__ dst,
                               const float* __restrict__ ea, int* __restrict__ cursor,
                               int2* __restrict__ epack, int E) {
  int j = blockIdx.x * blockDim.x + threadIdx.x;
  if (j >= E) return;
  int d = dst[j];
  int pos = atomicAdd(&cursor[d], 1);
  epack[pos] = make_int2(src[j], __float_as_int(ea[j]));
}

// ---------- Layer 1 gather: thread-per-node, low VGPR, high occupancy --------
__global__ void __launch_bounds__(256, 8) gather1_kernel(
    const float* __restrict__ x, const int* __restrict__ rowptr,
    const int2* __restrict__ epack,
    const float* __restrict__ we1, const float* __restrict__ be1,
    float* __restrict__ xin, int N) {
  int i = blockIdx.x * blockDim.x + threadIdx.x;
  if (i >= N) return;
  float we[9], be[9];
#pragma unroll
  for (int f = 0; f < 9; ++f) { we[f] = we1[f]; be[f] = be1[f]; }
  float acc[9];
#pragma unroll
  for (int f = 0; f < 9; ++f) acc[f] = 0.0f;

  int p0 = rowptr[i], p1 = rowptr[i + 1];
  int p = p0;
  for (; p + 1 < p1; p += 2) {
    int2 e0 = epack[p], e1 = epack[p + 1];
    float a0 = __int_as_float(e0.y), a1 = __int_as_float(e1.y);
    float r0[9], r1[9];
#pragma unroll
    for (int f = 0; f < 9; ++f) r0[f] = x[(size_t)e0.x * 9 + f];
#pragma unroll
    for (int f = 0; f < 9; ++f) r1[f] = x[(size_t)e1.x * 9 + f];
#pragma unroll
    for (int f = 0; f < 9; ++f) {
      acc[f] += fmaxf(fmaf(a0, we[f], be[f]) + r0[f], 0.0f);
      acc[f] += fmaxf(fmaf(a1, we[f], be[f]) + r1[f], 0.0f);
    }
  }
  for (; p < p1; ++p) {
    int2 e = epack[p];
    float a = __int_as_float(e.y);
#pragma unroll
    for (int f = 0; f < 9; ++f)
      acc[f] += fmaxf(fmaf(a, we[f], be[f]) + x[(size_t)e.x * 9 + f], 0.0f);
  }
#pragma unroll
  for (int f = 0; f < 9; ++f) xin[(size_t)i * 9 + f] = x[(size_t)i * 9 + f] + acc[f];
}

// ---------- Layer 1 MLP: h1 = relu(relu(xin@w11+b11)@w12+b12) ----------------
// (256,3): VGPR cap ~170 so t1[64] stays in registers (R5: (256,4) spilled).
__global__ void __launch_bounds__(256, 3) node1_mlp(
    const float* __restrict__ xin,
    const float* __restrict__ w11, const float* __restrict__ b11,
    const float* __restrict__ w12, const float* __restrict__ b12,
    float* __restrict__ h1, int N) {
  __shared__ float sW1[9 * 64];
  __shared__ float sB1[64];
  __shared__ float sW2[64 * 64];
  __shared__ float sB2[64];
  for (int t = threadIdx.x; t < 9 * 64; t += blockDim.x) sW1[t] = w11[t];
  for (int t = threadIdx.x; t < 64; t += blockDim.x) { sB1[t] = b11[t]; sB2[t] = b12[t]; }
  for (int t = threadIdx.x; t < 64 * 64; t += blockDim.x) sW2[t] = w12[t];
  __syncthreads();
  int i = blockIdx.x * blockDim.x + threadIdx.x;
  if (i >= N) return;
  float xv[9];
#pragma unroll
  for (int k = 0; k < 9; ++k) xv[k] = xin[(size_t)i * 9 + k];
  float t1[64];
#pragma unroll
  for (int o = 0; o < 64; ++o) {
    float a = sB1[o];
#pragma unroll
    for (int k = 0; k < 9; ++k) a = fmaf(xv[k], sW1[k * 64 + o], a);
    t1[o] = fmaxf(a, 0.0f);
  }
  for (int o = 0; o < 64; ++o) {
    float a = sB2[o];
#pragma unroll
    for (int k = 0; k < 64; ++k) a = fmaf(t1[k], sW2[k * 64 + o], a);
    h1[(size_t)i * 64 + o] = fmaxf(a, 0.0f);
  }
}

// ---------- Layer 2 gather: wave-per-node, no LDS, unroll-4 ------------------
__global__ void __launch_bounds__(256, 8) gather2_kernel(
    const float* __restrict__ h1, const int* __restrict__ rowptr,
    const int2* __restrict__ epack,
    const float* __restrict__ we2, const float* __restrict__ be2,
    float* __restrict__ agg2, int N) {
  int wid = threadIdx.x >> 6;
  int lane = threadIdx.x & 63;
  int i = blockIdx.x * 4 + wid;
  if (i >= N) return;

  float we_l = we2[lane], be_l = be2[lane];
  float acc = 0.0f;
  int p0 = rowptr[i], p1 = rowptr[i + 1];
  int p = p0;
  for (; p + 3 < p1; p += 4) {
    int2 e0 = epack[p], e1 = epack[p + 1], e2 = epack[p + 2], e3 = epack[p + 3];
    float h0 = h1[(size_t)e0.x * 64 + lane];
    float hv1 = h1[(size_t)e1.x * 64 + lane];
    float h2 = h1[(size_t)e2.x * 64 + lane];
    float h3 = h1[(size_t)e3.x * 64 + lane];
    acc += fmaxf(fmaf(__int_as_float(e0.y), we_l, be_l) + h0, 0.0f);
    acc += fmaxf(fmaf(__int_as_float(e1.y), we_l, be_l) + hv1, 0.0f);
    acc += fmaxf(fmaf(__int_as_float(e2.y), we_l, be_l) + h2, 0.0f);
    acc += fmaxf(fmaf(__int_as_float(e3.y), we_l, be_l) + h3, 0.0f);
  }
  for (; p < p1; ++p) {
    int2 e = epack[p];
    acc += fmaxf(fmaf(__int_as_float(e.y), we_l, be_l) + h1[(size_t)e.x * 64 + lane], 0.0f);
  }
  agg2[(size_t)i * 64 + lane] = acc;
}

// ---------- Layer 2 node MLP + readout: raw[i] (thread per node) -------------
__global__ void __launch_bounds__(256, 3) node2_kernel(
    const float* __restrict__ h1, const float* __restrict__ agg2,
    const float* __restrict__ w21, const float* __restrict__ b21,
    const float* __restrict__ w22, const float* __restrict__ b22,
    const float* __restrict__ wr1, const float* __restrict__ br1,
    const float* __restrict__ wr2, const float* __restrict__ br2,
    float* __restrict__ raw, int N) {
  __shared__ float sW1[64 * 64];
  __shared__ float sB1[64];
  __shared__ float sW2[64 * 64];
  __shared__ float sB2[64];
  __shared__ float sWr1[64 * 32];
  __shared__ float sBr1[32];
  __shared__ float sWr2[32];
  __shared__ float sBr2;
  for (int t = threadIdx.x; t < 64 * 64; t += blockDim.x) { sW1[t] = w21[t]; sW2[t] = w22[t]; }
  for (int t = threadIdx.x; t < 64; t += blockDim.x) { sB1[t] = b21[t]; sB2[t] = b22[t]; }
  for (int t = threadIdx.x; t < 64 * 32; t += blockDim.x) sWr1[t] = wr1[t];
  for (int t = threadIdx.x; t < 32; t += blockDim.x) { sBr1[t] = br1[t]; sWr2[t] = wr2[t]; }
  if (threadIdx.x == 0) sBr2 = br2[0];
  __syncthreads();
  int i = blockIdx.x * blockDim.x + threadIdx.x;
  if (i >= N) return;
  float hin[64];
#pragma unroll
  for (int k = 0; k < 64; ++k) hin[k] = h1[(size_t)i * 64 + k] + agg2[(size_t)i * 64 + k];
  float a1[64];
  for (int o = 0; o < 64; ++o) {
    float acc = sB1[o];
#pragma unroll
    for (int k = 0; k < 64; ++k) acc = fmaf(hin[k], sW1[k * 64 + o], acc);
    a1[o] = fmaxf(acc, 0.0f);
  }
  float a2[64];
  for (int o = 0; o < 64; ++o) {
    float acc = sB2[o];
#pragma unroll
    for (int k = 0; k < 64; ++k) acc = fmaf(a1[k], sW2[k * 64 + o], acc);
    a2[o] = fmaxf(acc, 0.0f);
  }
  float r[32];
  for (int o = 0; o < 32; ++o) {
    float acc = sBr1[o];
#pragma unroll
    for (int k = 0; k < 64; ++k) acc = fmaf(a2[k], sWr1[k * 32 + o], acc);
    r[o] = fmaxf(acc, 0.0f);
  }
  float acc = sBr2;
#pragma unroll
  for (int k = 0; k < 32; ++k) acc = fmaf(r[k], sWr2[k], acc);
  raw[i] = acc;
}

// ---------- Segment softmax --------------------------------------------------
__global__ void segmax_kernel(const float* __restrict__ raw, const int* __restrict__ batch,
                              unsigned* __restrict__ gmax, int N) {
  int i = blockIdx.x * blockDim.x + threadIdx.x;
  if (i >= N) return;
  atomicMax(&gmax[batch[i]], fkey(raw[i]));
}

__global__ void expsum_kernel(const float* __restrict__ raw, const int* __restrict__ batch,
                              const unsigned* __restrict__ gmax, float* __restrict__ z,
                              float* __restrict__ gsum, int N) {
  int i = blockIdx.x * blockDim.x + threadIdx.x;
  if (i >= N) return;
  int b = batch[i];
  float zz = expf(raw[i] - funkey(gmax[b]));
  z[i] = zz;
  atomicAdd(&gsum[b], zz);
}

__global__ void final_kernel(const float* __restrict__ z, const int* __restrict__ batch,
                             const float* __restrict__ gsum, const float* __restrict__ Btot,
                             float* __restrict__ out, int N) {
  int i = blockIdx.x * blockDim.x + threadIdx.x;
  if (i >= N) return;
  int b = batch[i];
  out[i] = z[i] / gsum[b] * Btot[b];
}

extern "C" void kernel_launch(void* const* d_in, const int* in_sizes, int n_in,
                              void* d_out, int out_size, void* d_ws, size_t ws_size,
                              hipStream_t stream) {
  const float* x     = (const float*)d_in[0];
  const int* eidx    = (const int*)d_in[1];
  const float* eattr = (const float*)d_in[2];
  const int* batch   = (const int*)d_in[3];
  const float* Btot  = (const float*)d_in[4];
  const float* we1 = (const float*)d_in[5];
  const float* be1 = (const float*)d_in[6];
  const float* w11 = (const float*)d_in[7];
  const float* b11 = (const float*)d_in[8];
  const float* w12 = (const float*)d_in[9];
  const float* b12 = (const float*)d_in[10];
  const float* we2 = (const float*)d_in[11];
  const float* be2 = (const float*)d_in[12];
  const float* w21 = (const float*)d_in[13];
  const float* b21 = (const float*)d_in[14];
  const float* w22 = (const float*)d_in[15];
  const float* b22 = (const float*)d_in[16];
  const float* wr1 = (const float*)d_in[17];
  const float* br1 = (const float*)d_in[18];
  const float* wr2 = (const float*)d_in[19];
  const float* br2 = (const float*)d_in[20];

  const int N  = in_sizes[0] / 9;     // 100000
  const int E  = in_sizes[2];         // 1600000
  const int NG = in_sizes[4];         // 1000
  const int* src = eidx;
  const int* dst = eidx + E;

  const int NB = (N + 1023) / 1024;   // scan blocks (98)

  // workspace layout (all 4-byte elems)
  char* w = (char*)d_ws;
  int*   deg    = (int*)w;                 w += (size_t)N * 4;
  int*   rowptr = (int*)w;                 w += (size_t)(N + 1) * 4;
  int*   cursor = (int*)w;                 w += (size_t)N * 4;
  int*   blocksum = (int*)w;               w += (size_t)1024 * 4;
  int2*  epack  = (int2*)w;                w += (size_t)E * 8;
  float* h1     = (float*)w;               w += (size_t)N * 64 * 4;
  float* agg2   = (float*)w;               w += (size_t)N * 64 * 4;
  float* raw    = (float*)w;               w += (size_t)N * 4;
  float* z      = (float*)w;               w += (size_t)N * 4;
  unsigned* gmax = (unsigned*)w;           w += (size_t)NG * 4;
  float* gsum   = (float*)w;               w += (size_t)NG * 4;
  // xin[N*9] aliases agg2 (dead until gather2, which fully overwrites it)
  float* xin = agg2;

  hipMemsetAsync(deg, 0, (size_t)N * 4, stream);
  hipMemsetAsync(gmax, 0, (size_t)NG * 8, stream);  // gmax + gsum (contiguous)

  dim3 blk(256);
  dim3 egrid((E + 255) / 256);
  dim3 ngrid((N + 255) / 256);

  // CSR build (parallel 3-pass scan; pass3 also fills cursor)
  deg_kernel<<<egrid, blk, 0, stream>>>(dst, deg, E);
  scan_pass1<<<dim3(NB), dim3(1024), 0, stream>>>(deg, blocksum, N);
  scan_pass2<<<dim3(1), dim3(1024), 0, stream>>>(blocksum, NB);
  scan_pass3<<<dim3(NB), dim3(1024), 0, stream>>>(deg, blocksum, rowptr, cursor, N, E);
  scatter_kernel<<<egrid, blk, 0, stream>>>(src, dst, eattr, cursor, epack, E);

  // layer 1: gather then MLP
  gather1_kernel<<<ngrid, blk, 0, stream>>>(x, rowptr, epack, we1, be1, xin, N);
  node1_mlp<<<ngrid, blk, 0, stream>>>(xin, w11, b11, w12, b12, h1, N);

  // layer 2: gather then MLP (+readout)
  dim3 l2grid((N + 3) / 4);
  gather2_kernel<<<l2grid, blk, 0, stream>>>(h1, rowptr, epack, we2, be2, agg2, N);
  node2_kernel<<<ngrid, blk, 0, stream>>>(h1, agg2, w21, b21, w22, b22,
                                          wr1, br1, wr2, br2, raw, N);

  // segment softmax + scale
  segmax_kernel<<<ngrid, blk, 0, stream>>>(raw, batch, gmax, N);
  expsum_kernel<<<ngrid, blk, 0, stream>>>(raw, batch, gmax, z, gsum, N);
  final_kernel<<<ngrid, blk, 0, stream>>>(z, batch, gsum, Btot, (float*)d_out, N);
}

// Round 7
// 454.952 us; speedup vs baseline: 3.1135x; 1.2077x over previous
//
#include <hip/hip_runtime.h>
#include <float.h>

// ---------- CSR build ---------------------------------------------------------
// deg + per-edge rank in one pass; rank write is coalesced.
__global__ void deg_rank_kernel(const int* __restrict__ dst, int* __restrict__ deg,
                                int* __restrict__ rank, int E) {
  int j = blockIdx.x * blockDim.x + threadIdx.x;
  if (j < E) rank[j] = atomicAdd(&deg[dst[j]], 1);
}

// ---- hierarchical exclusive scan over deg[N] (3 passes, all parallel) -------
__global__ void scan_pass1(const int* __restrict__ deg, int* __restrict__ blocksum, int N) {
  __shared__ int sdata[1024];
  int i = blockIdx.x * 1024 + threadIdx.x;
  sdata[threadIdx.x] = (i < N) ? deg[i] : 0;
  __syncthreads();
  for (int s = 512; s > 0; s >>= 1) {
    if (threadIdx.x < s) sdata[threadIdx.x] += sdata[threadIdx.x + s];
    __syncthreads();
  }
  if (threadIdx.x == 0) blocksum[blockIdx.x] = sdata[0];
}

__global__ void scan_pass2(int* __restrict__ blocksum, int nb) {
  __shared__ int sdata[1024];
  int t = threadIdx.x;
  sdata[t] = (t < nb) ? blocksum[t] : 0;
  __syncthreads();
  if (t == 0) {
    int run = 0;
    for (int i = 0; i < nb; ++i) { int v = sdata[i]; sdata[i] = run; run += v; }
  }
  __syncthreads();
  if (t < nb) blocksum[t] = sdata[t];
}

__global__ void scan_pass3(const int* __restrict__ deg, const int* __restrict__ blocksum,
                           int* __restrict__ rowptr, int N, int E) {
  __shared__ int sdata[1024];
  int i = blockIdx.x * 1024 + threadIdx.x;
  int v = (i < N) ? deg[i] : 0;
  sdata[threadIdx.x] = v;
  __syncthreads();
  for (int off = 1; off < 1024; off <<= 1) {
    int t = (threadIdx.x >= off) ? sdata[threadIdx.x - off] : 0;
    __syncthreads();
    sdata[threadIdx.x] += t;
    __syncthreads();
  }
  if (i < N) rowptr[i] = blocksum[blockIdx.x] + sdata[threadIdx.x] - v;  // exclusive
  if (i == 0) rowptr[N] = E;
}

// pure 4B scatter, no atomics (rank precomputed)
__global__ void scatter_kernel(const int* __restrict__ dst, const int* __restrict__ rank,
                               const int* __restrict__ rowptr, int* __restrict__ seid, int E) {
  int j = blockIdx.x * blockDim.x + threadIdx.x;
  if (j >= E) return;
  seid[rowptr[dst[j]] + rank[j]] = j;
}

// ---------- Layer 1 gather: thread-per-node, low VGPR, high occupancy --------
__global__ void __launch_bounds__(256, 8) gather1_kernel(
    const float* __restrict__ x, const int* __restrict__ rowptr,
    const int* __restrict__ seid, const int* __restrict__ src, const float* __restrict__ ea,
    const float* __restrict__ we1, const float* __restrict__ be1,
    float* __restrict__ xin, int N) {
  int i = blockIdx.x * blockDim.x + threadIdx.x;
  if (i >= N) return;
  float we[9], be[9];
#pragma unroll
  for (int f = 0; f < 9; ++f) { we[f] = we1[f]; be[f] = be1[f]; }
  float acc[9];
#pragma unroll
  for (int f = 0; f < 9; ++f) acc[f] = 0.0f;

  int p0 = rowptr[i], p1 = rowptr[i + 1];
  int p = p0;
  for (; p + 1 < p1; p += 2) {
    int e0 = seid[p], e1 = seid[p + 1];
    int s0 = src[e0], s1 = src[e1];
    float a0 = ea[e0], a1 = ea[e1];
    float r0[9], r1[9];
#pragma unroll
    for (int f = 0; f < 9; ++f) r0[f] = x[(size_t)s0 * 9 + f];
#pragma unroll
    for (int f = 0; f < 9; ++f) r1[f] = x[(size_t)s1 * 9 + f];
#pragma unroll
    for (int f = 0; f < 9; ++f) {
      acc[f] += fmaxf(fmaf(a0, we[f], be[f]) + r0[f], 0.0f);
      acc[f] += fmaxf(fmaf(a1, we[f], be[f]) + r1[f], 0.0f);
    }
  }
  for (; p < p1; ++p) {
    int e = seid[p];
    int s = src[e];
    float a = ea[e];
#pragma unroll
    for (int f = 0; f < 9; ++f)
      acc[f] += fmaxf(fmaf(a, we[f], be[f]) + x[(size_t)s * 9 + f], 0.0f);
  }
#pragma unroll
  for (int f = 0; f < 9; ++f) xin[(size_t)i * 9 + f] = x[(size_t)i * 9 + f] + acc[f];
}

// ---------- Layer 1 MLP ------------------------------------------------------
__global__ void __launch_bounds__(256, 3) node1_mlp(
    const float* __restrict__ xin,
    const float* __restrict__ w11, const float* __restrict__ b11,
    const float* __restrict__ w12, const float* __restrict__ b12,
    float* __restrict__ h1, int N) {
  __shared__ float sW1[9 * 64];
  __shared__ float sB1[64];
  __shared__ float sW2[64 * 64];
  __shared__ float sB2[64];
  for (int t = threadIdx.x; t < 9 * 64; t += blockDim.x) sW1[t] = w11[t];
  for (int t = threadIdx.x; t < 64; t += blockDim.x) { sB1[t] = b11[t]; sB2[t] = b12[t]; }
  for (int t = threadIdx.x; t < 64 * 64; t += blockDim.x) sW2[t] = w12[t];
  __syncthreads();
  int i = blockIdx.x * blockDim.x + threadIdx.x;
  if (i >= N) return;
  float xv[9];
#pragma unroll
  for (int k = 0; k < 9; ++k) xv[k] = xin[(size_t)i * 9 + k];
  float t1[64];
#pragma unroll
  for (int o = 0; o < 64; ++o) {
    float a = sB1[o];
#pragma unroll
    for (int k = 0; k < 9; ++k) a = fmaf(xv[k], sW1[k * 64 + o], a);
    t1[o] = fmaxf(a, 0.0f);
  }
  for (int o = 0; o < 64; ++o) {
    float a = sB2[o];
#pragma unroll
    for (int k = 0; k < 64; ++k) a = fmaf(t1[k], sW2[k * 64 + o], a);
    h1[(size_t)i * 64 + o] = fmaxf(a, 0.0f);
  }
}

// ---------- Layer 2 gather: wave-per-node, no LDS, unroll-4 ------------------
__global__ void __launch_bounds__(256, 8) gather2_kernel(
    const float* __restrict__ h1, const int* __restrict__ rowptr,
    const int* __restrict__ seid, const int* __restrict__ src, const float* __restrict__ ea,
    const float* __restrict__ we2, const float* __restrict__ be2,
    float* __restrict__ agg2, int N) {
  int wid = threadIdx.x >> 6;
  int lane = threadIdx.x & 63;
  int i = blockIdx.x * 4 + wid;
  if (i >= N) return;

  float we_l = we2[lane], be_l = be2[lane];
  float acc = 0.0f;
  int p0 = rowptr[i], p1 = rowptr[i + 1];
  int p = p0;
  for (; p + 3 < p1; p += 4) {
    int e0 = seid[p], e1 = seid[p + 1], e2 = seid[p + 2], e3 = seid[p + 3];
    int s0 = src[e0], s1 = src[e1], s2 = src[e2], s3 = src[e3];
    float a0 = ea[e0], a1 = ea[e1], a2 = ea[e2], a3 = ea[e3];
    float h0 = h1[(size_t)s0 * 64 + lane];
    float hv1 = h1[(size_t)s1 * 64 + lane];
    float h2 = h1[(size_t)s2 * 64 + lane];
    float h3 = h1[(size_t)s3 * 64 + lane];
    acc += fmaxf(fmaf(a0, we_l, be_l) + h0, 0.0f);
    acc += fmaxf(fmaf(a1, we_l, be_l) + hv1, 0.0f);
    acc += fmaxf(fmaf(a2, we_l, be_l) + h2, 0.0f);
    acc += fmaxf(fmaf(a3, we_l, be_l) + h3, 0.0f);
  }
  for (; p < p1; ++p) {
    int e = seid[p];
    acc += fmaxf(fmaf(ea[e], we_l, be_l) + h1[(size_t)src[e] * 64 + lane], 0.0f);
  }
  agg2[(size_t)i * 64 + lane] = acc;
}

// ---------- Layer 2 node MLP + readout ---------------------------------------
__global__ void __launch_bounds__(256, 3) node2_kernel(
    const float* __restrict__ h1, const float* __restrict__ agg2,
    const float* __restrict__ w21, const float* __restrict__ b21,
    const float* __restrict__ w22, const float* __restrict__ b22,
    const float* __restrict__ wr1, const float* __restrict__ br1,
    const float* __restrict__ wr2, const float* __restrict__ br2,
    float* __restrict__ raw, int N) {
  __shared__ float sW1[64 * 64];
  __shared__ float sB1[64];
  __shared__ float sW2[64 * 64];
  __shared__ float sB2[64];
  __shared__ float sWr1[64 * 32];
  __shared__ float sBr1[32];
  __shared__ float sWr2[32];
  __shared__ float sBr2;
  for (int t = threadIdx.x; t < 64 * 64; t += blockDim.x) { sW1[t] = w21[t]; sW2[t] = w22[t]; }
  for (int t = threadIdx.x; t < 64; t += blockDim.x) { sB1[t] = b21[t]; sB2[t] = b22[t]; }
  for (int t = threadIdx.x; t < 64 * 32; t += blockDim.x) sWr1[t] = wr1[t];
  for (int t = threadIdx.x; t < 32; t += blockDim.x) { sBr1[t] = br1[t]; sWr2[t] = wr2[t]; }
  if (threadIdx.x == 0) sBr2 = br2[0];
  __syncthreads();
  int i = blockIdx.x * blockDim.x + threadIdx.x;
  if (i >= N) return;
  float hin[64];
#pragma unroll
  for (int k = 0; k < 64; ++k) hin[k] = h1[(size_t)i * 64 + k] + agg2[(size_t)i * 64 + k];
  float a1[64];
  for (int o = 0; o < 64; ++o) {
    float acc = sB1[o];
#pragma unroll
    for (int k = 0; k < 64; ++k) acc = fmaf(hin[k], sW1[k * 64 + o], acc);
    a1[o] = fmaxf(acc, 0.0f);
  }
  float a2[64];
  for (int o = 0; o < 64; ++o) {
    float acc = sB2[o];
#pragma unroll
    for (int k = 0; k < 64; ++k) acc = fmaf(a1[k], sW2[k * 64 + o], acc);
    a2[o] = fmaxf(acc, 0.0f);
  }
  float r[32];
  for (int o = 0; o < 32; ++o) {
    float acc = sBr1[o];
#pragma unroll
    for (int k = 0; k < 64; ++k) acc = fmaf(a2[k], sWr1[k * 32 + o], acc);
    r[o] = fmaxf(acc, 0.0f);
  }
  float acc = sBr2;
#pragma unroll
  for (int k = 0; k < 32; ++k) acc = fmaf(r[k], sWr2[k], acc);
  raw[i] = acc;
}

// ---------- Fused segment softmax: one block per graph (batch is sorted) -----
__device__ __forceinline__ int lowerb(const int* __restrict__ a, int n, int key) {
  int lo = 0, hi = n;
  while (lo < hi) { int mid = (lo + hi) >> 1; if (a[mid] < key) lo = mid + 1; else hi = mid; }
  return lo;
}

__global__ void segsoftmax_kernel(const float* __restrict__ raw, const int* __restrict__ batch,
                                  const float* __restrict__ Btot, float* __restrict__ out, int N) {
  __shared__ float sred[256];
  int g = blockIdx.x;
  int tid = threadIdx.x;
  int start = lowerb(batch, N, g);
  int end = lowerb(batch, N, g + 1);
  if (start >= end) return;

  float m = -FLT_MAX;
  for (int i = start + tid; i < end; i += 256) m = fmaxf(m, raw[i]);
  sred[tid] = m;
  __syncthreads();
  for (int s = 128; s > 0; s >>= 1) {
    if (tid < s) sred[tid] = fmaxf(sred[tid], sred[tid + s]);
    __syncthreads();
  }
  m = sred[0];
  __syncthreads();

  float sum = 0.0f;
  for (int i = start + tid; i < end; i += 256) sum += expf(raw[i] - m);
  sred[tid] = sum;
  __syncthreads();
  for (int s = 128; s > 0; s >>= 1) {
    if (tid < s) sred[tid] += sred[tid + s];
    __syncthreads();
  }
  float scale = Btot[g] / sred[0];

  for (int i = start + tid; i < end; i += 256) out[i] = expf(raw[i] - m) * scale;
}

extern "C" void kernel_launch(void* const* d_in, const int* in_sizes, int n_in,
                              void* d_out, int out_size, void* d_ws, size_t ws_size,
                              hipStream_t stream) {
  const float* x     = (const float*)d_in[0];
  const int* eidx    = (const int*)d_in[1];
  const float* eattr = (const float*)d_in[2];
  const int* batch   = (const int*)d_in[3];
  const float* Btot  = (const float*)d_in[4];
  const float* we1 = (const float*)d_in[5];
  const float* be1 = (const float*)d_in[6];
  const float* w11 = (const float*)d_in[7];
  const float* b11 = (const float*)d_in[8];
  const float* w12 = (const float*)d_in[9];
  const float* b12 = (const float*)d_in[10];
  const float* we2 = (const float*)d_in[11];
  const float* be2 = (const float*)d_in[12];
  const float* w21 = (const float*)d_in[13];
  const float* b21 = (const float*)d_in[14];
  const float* w22 = (const float*)d_in[15];
  const float* b22 = (const float*)d_in[16];
  const float* wr1 = (const float*)d_in[17];
  const float* br1 = (const float*)d_in[18];
  const float* wr2 = (const float*)d_in[19];
  const float* br2 = (const float*)d_in[20];

  const int N  = in_sizes[0] / 9;     // 100000
  const int E  = in_sizes[2];         // 1600000
  const int NG = in_sizes[4];         // 1000
  const int* src = eidx;
  const int* dst = eidx + E;

  const int NB = (N + 1023) / 1024;   // scan blocks (98)

  // workspace layout
  char* w = (char*)d_ws;
  int*   deg    = (int*)w;                 w += (size_t)N * 4;
  int*   rowptr = (int*)w;                 w += (size_t)(N + 1) * 4;
  int*   blocksum = (int*)w;               w += (size_t)1024 * 4;
  int*   rank   = (int*)w;                 w += (size_t)E * 4;
  int*   seid   = (int*)w;                 w += (size_t)E * 4;
  float* h1     = (float*)w;               w += (size_t)N * 64 * 4;
  float* agg2   = (float*)w;               w += (size_t)N * 64 * 4;
  float* raw    = (float*)w;               w += (size_t)N * 4;
  // xin[N*9] aliases agg2 (dead until gather2, which fully overwrites it)
  float* xin = agg2;

  hipMemsetAsync(deg, 0, (size_t)N * 4, stream);

  dim3 blk(256);
  dim3 egrid((E + 255) / 256);
  dim3 ngrid((N + 255) / 256);

  // CSR build: deg+rank, 3-pass scan, atomic-free 4B scatter
  deg_rank_kernel<<<egrid, blk, 0, stream>>>(dst, deg, rank, E);
  scan_pass1<<<dim3(NB), dim3(1024), 0, stream>>>(deg, blocksum, N);
  scan_pass2<<<dim3(1), dim3(1024), 0, stream>>>(blocksum, NB);
  scan_pass3<<<dim3(NB), dim3(1024), 0, stream>>>(deg, blocksum, rowptr, N, E);
  scatter_kernel<<<egrid, blk, 0, stream>>>(dst, rank, rowptr, seid, E);

  // layer 1: gather then MLP
  gather1_kernel<<<ngrid, blk, 0, stream>>>(x, rowptr, seid, src, eattr, we1, be1, xin, N);
  node1_mlp<<<ngrid, blk, 0, stream>>>(xin, w11, b11, w12, b12, h1, N);

  // layer 2: gather then MLP (+readout)
  dim3 l2grid((N + 3) / 4);
  gather2_kernel<<<l2grid, blk, 0, stream>>>(h1, rowptr, seid, src, eattr, we2, be2, agg2, N);
  node2_kernel<<<ngrid, blk, 0, stream>>>(h1, agg2, w21, b21, w22, b22,
                                          wr1, br1, wr2, br2, raw, N);

  // fused segment softmax + scale (one block per graph; batch sorted)
  segsoftmax_kernel<<<dim3(NG), blk, 0, stream>>>(raw, batch, Btot, (float*)d_out, N);
}

// Round 8
// 429.655 us; speedup vs baseline: 3.2968x; 1.0589x over previous
//
#include <hip/hip_runtime.h>
#include <float.h>

// ---------- CSR build ---------------------------------------------------------
__global__ void deg_rank_kernel(const int* __restrict__ dst, int* __restrict__ deg,
                                int* __restrict__ rank, int E) {
  int j = blockIdx.x * blockDim.x + threadIdx.x;
  if (j < E) rank[j] = atomicAdd(&deg[dst[j]], 1);
}

__global__ void scan_pass1(const int* __restrict__ deg, int* __restrict__ blocksum, int N) {
  __shared__ int sdata[1024];
  int i = blockIdx.x * 1024 + threadIdx.x;
  sdata[threadIdx.x] = (i < N) ? deg[i] : 0;
  __syncthreads();
  for (int s = 512; s > 0; s >>= 1) {
    if (threadIdx.x < s) sdata[threadIdx.x] += sdata[threadIdx.x + s];
    __syncthreads();
  }
  if (threadIdx.x == 0) blocksum[blockIdx.x] = sdata[0];
}

__global__ void scan_pass2(int* __restrict__ blocksum, int nb) {
  __shared__ int sdata[1024];
  int t = threadIdx.x;
  sdata[t] = (t < nb) ? blocksum[t] : 0;
  __syncthreads();
  if (t == 0) {
    int run = 0;
    for (int i = 0; i < nb; ++i) { int v = sdata[i]; sdata[i] = run; run += v; }
  }
  __syncthreads();
  if (t < nb) blocksum[t] = sdata[t];
}

__global__ void scan_pass3(const int* __restrict__ deg, const int* __restrict__ blocksum,
                           int* __restrict__ rowptr, int N, int E) {
  __shared__ int sdata[1024];
  int i = blockIdx.x * 1024 + threadIdx.x;
  int v = (i < N) ? deg[i] : 0;
  sdata[threadIdx.x] = v;
  __syncthreads();
  for (int off = 1; off < 1024; off <<= 1) {
    int t = (threadIdx.x >= off) ? sdata[threadIdx.x - off] : 0;
    __syncthreads();
    sdata[threadIdx.x] += t;
    __syncthreads();
  }
  if (i < N) rowptr[i] = blocksum[blockIdx.x] + sdata[threadIdx.x] - v;  // exclusive
  if (i == 0) rowptr[N] = E;
}

__global__ void scatter_kernel(const int* __restrict__ dst, const int* __restrict__ rank,
                               const int* __restrict__ rowptr, int* __restrict__ seid, int E) {
  int j = blockIdx.x * blockDim.x + threadIdx.x;
  if (j >= E) return;
  seid[rowptr[dst[j]] + rank[j]] = j;
}

// ---------- Layer 1 gather: thread-per-node ----------------------------------
__global__ void __launch_bounds__(256, 8) gather1_kernel(
    const float* __restrict__ x, const int* __restrict__ rowptr,
    const int* __restrict__ seid, const int* __restrict__ src, const float* __restrict__ ea,
    const float* __restrict__ we1, const float* __restrict__ be1,
    float* __restrict__ xin, int N) {
  int i = blockIdx.x * blockDim.x + threadIdx.x;
  if (i >= N) return;
  float we[9], be[9];
#pragma unroll
  for (int f = 0; f < 9; ++f) { we[f] = we1[f]; be[f] = be1[f]; }
  float acc[9];
#pragma unroll
  for (int f = 0; f < 9; ++f) acc[f] = 0.0f;

  int p0 = rowptr[i], p1 = rowptr[i + 1];
  int p = p0;
  for (; p + 1 < p1; p += 2) {
    int e0 = seid[p], e1 = seid[p + 1];
    int s0 = src[e0], s1 = src[e1];
    float a0 = ea[e0], a1 = ea[e1];
    float r0[9], r1[9];
#pragma unroll
    for (int f = 0; f < 9; ++f) r0[f] = x[(size_t)s0 * 9 + f];
#pragma unroll
    for (int f = 0; f < 9; ++f) r1[f] = x[(size_t)s1 * 9 + f];
#pragma unroll
    for (int f = 0; f < 9; ++f) {
      acc[f] += fmaxf(fmaf(a0, we[f], be[f]) + r0[f], 0.0f);
      acc[f] += fmaxf(fmaf(a1, we[f], be[f]) + r1[f], 0.0f);
    }
  }
  for (; p < p1; ++p) {
    int e = seid[p];
    int s = src[e];
    float a = ea[e];
#pragma unroll
    for (int f = 0; f < 9; ++f)
      acc[f] += fmaxf(fmaf(a, we[f], be[f]) + x[(size_t)s * 9 + f], 0.0f);
  }
#pragma unroll
  for (int f = 0; f < 9; ++f) xin[(size_t)i * 9 + f] = x[(size_t)i * 9 + f] + acc[f];
}

// ---------- Layer 1 MLP ------------------------------------------------------
__global__ void __launch_bounds__(256, 3) node1_mlp(
    const float* __restrict__ xin,
    const float* __restrict__ w11, const float* __restrict__ b11,
    const float* __restrict__ w12, const float* __restrict__ b12,
    float* __restrict__ h1, int N) {
  __shared__ float sW1[9 * 64];
  __shared__ float sB1[64];
  __shared__ float sW2[64 * 64];
  __shared__ float sB2[64];
  for (int t = threadIdx.x; t < 9 * 64; t += blockDim.x) sW1[t] = w11[t];
  for (int t = threadIdx.x; t < 64; t += blockDim.x) { sB1[t] = b11[t]; sB2[t] = b12[t]; }
  for (int t = threadIdx.x; t < 64 * 64; t += blockDim.x) sW2[t] = w12[t];
  __syncthreads();
  int i = blockIdx.x * blockDim.x + threadIdx.x;
  if (i >= N) return;
  float xv[9];
#pragma unroll
  for (int k = 0; k < 9; ++k) xv[k] = xin[(size_t)i * 9 + k];
  float t1[64];
#pragma unroll
  for (int o = 0; o < 64; ++o) {
    float a = sB1[o];
#pragma unroll
    for (int k = 0; k < 9; ++k) a = fmaf(xv[k], sW1[k * 64 + o], a);
    t1[o] = fmaxf(a, 0.0f);
  }
  for (int o = 0; o < 64; ++o) {
    float a = sB2[o];
#pragma unroll
    for (int k = 0; k < 64; ++k) a = fmaf(t1[k], sW2[k * 64 + o], a);
    h1[(size_t)i * 64 + o] = fmaxf(a, 0.0f);
  }
}

// ---------- Layer 2 gather: wave-per-node, 16-lanes-per-edge, float4 ---------
// 4 lane-groups of 16; each group processes its own edge sublist with
// float4 (dwordx4) h1-row loads; cross-group reduce via shfl at the end.
__global__ void __launch_bounds__(256, 8) gather2_kernel(
    const float* __restrict__ h1, const int* __restrict__ rowptr,
    const int* __restrict__ seid, const int* __restrict__ src, const float* __restrict__ ea,
    const float* __restrict__ we2, const float* __restrict__ be2,
    float* __restrict__ agg2, int N) {
  int wid = threadIdx.x >> 6;
  int lane = threadIdx.x & 63;
  int g = lane >> 4;          // edge group 0..3
  int l = lane & 15;          // sublane: features 4l..4l+3
  int i = blockIdx.x * 4 + wid;
  if (i >= N) return;

  float4 we_l = *(const float4*)(we2 + 4 * l);
  float4 be_l = *(const float4*)(be2 + 4 * l);
  float4 acc = make_float4(0.f, 0.f, 0.f, 0.f);

  int p0 = rowptr[i], p1 = rowptr[i + 1];
  int p = p0 + g;
  // unroll 2: two independent 256B row gathers in flight per group
  for (; p + 4 < p1; p += 8) {
    int e0 = seid[p], e1 = seid[p + 4];
    int s0 = src[e0], s1 = src[e1];
    float a0 = ea[e0], a1 = ea[e1];
    float4 h0 = *(const float4*)(h1 + (size_t)s0 * 64 + 4 * l);
    float4 hv = *(const float4*)(h1 + (size_t)s1 * 64 + 4 * l);
    acc.x += fmaxf(fmaf(a0, we_l.x, be_l.x) + h0.x, 0.f);
    acc.y += fmaxf(fmaf(a0, we_l.y, be_l.y) + h0.y, 0.f);
    acc.z += fmaxf(fmaf(a0, we_l.z, be_l.z) + h0.z, 0.f);
    acc.w += fmaxf(fmaf(a0, we_l.w, be_l.w) + h0.w, 0.f);
    acc.x += fmaxf(fmaf(a1, we_l.x, be_l.x) + hv.x, 0.f);
    acc.y += fmaxf(fmaf(a1, we_l.y, be_l.y) + hv.y, 0.f);
    acc.z += fmaxf(fmaf(a1, we_l.z, be_l.z) + hv.z, 0.f);
    acc.w += fmaxf(fmaf(a1, we_l.w, be_l.w) + hv.w, 0.f);
  }
  for (; p < p1; p += 4) {
    int e = seid[p];
    int s = src[e];
    float a = ea[e];
    float4 h = *(const float4*)(h1 + (size_t)s * 64 + 4 * l);
    acc.x += fmaxf(fmaf(a, we_l.x, be_l.x) + h.x, 0.f);
    acc.y += fmaxf(fmaf(a, we_l.y, be_l.y) + h.y, 0.f);
    acc.z += fmaxf(fmaf(a, we_l.z, be_l.z) + h.z, 0.f);
    acc.w += fmaxf(fmaf(a, we_l.w, be_l.w) + h.w, 0.f);
  }
  // reduce across the 4 groups (lanes l, l+16, l+32, l+48 hold same features)
#pragma unroll
  for (int off = 16; off <= 32; off <<= 1) {
    acc.x += __shfl_xor(acc.x, off);
    acc.y += __shfl_xor(acc.y, off);
    acc.z += __shfl_xor(acc.z, off);
    acc.w += __shfl_xor(acc.w, off);
  }
  if (g == 0) *(float4*)(agg2 + (size_t)i * 64 + 4 * l) = acc;
}

// ---------- Layer 2 node MLP + readout (fully unrolled: no scratch) ----------
__global__ void __launch_bounds__(256, 3) node2_kernel(
    const float* __restrict__ h1, const float* __restrict__ agg2,
    const float* __restrict__ w21, const float* __restrict__ b21,
    const float* __restrict__ w22, const float* __restrict__ b22,
    const float* __restrict__ wr1, const float* __restrict__ br1,
    const float* __restrict__ wr2, const float* __restrict__ br2,
    float* __restrict__ raw, int N) {
  __shared__ float sW1[64 * 64];
  __shared__ float sB1[64];
  __shared__ float sW2[64 * 64];
  __shared__ float sB2[64];
  __shared__ float sWr1[64 * 32];
  __shared__ float sBr1[32];
  __shared__ float sWr2[32];
  __shared__ float sBr2;
  for (int t = threadIdx.x; t < 64 * 64; t += blockDim.x) { sW1[t] = w21[t]; sW2[t] = w22[t]; }
  for (int t = threadIdx.x; t < 64; t += blockDim.x) { sB1[t] = b21[t]; sB2[t] = b22[t]; }
  for (int t = threadIdx.x; t < 64 * 32; t += blockDim.x) sWr1[t] = wr1[t];
  for (int t = threadIdx.x; t < 32; t += blockDim.x) { sBr1[t] = br1[t]; sWr2[t] = wr2[t]; }
  if (threadIdx.x == 0) sBr2 = br2[0];
  __syncthreads();
  int i = blockIdx.x * blockDim.x + threadIdx.x;
  if (i >= N) return;
  float hin[64];
#pragma unroll
  for (int k = 0; k < 64; ++k) hin[k] = h1[(size_t)i * 64 + k] + agg2[(size_t)i * 64 + k];
  float a1[64];
#pragma unroll
  for (int o = 0; o < 64; ++o) {
    float acc = sB1[o];
#pragma unroll
    for (int k = 0; k < 64; ++k) acc = fmaf(hin[k], sW1[k * 64 + o], acc);
    a1[o] = fmaxf(acc, 0.0f);
  }
  float a2[64];
#pragma unroll
  for (int o = 0; o < 64; ++o) {
    float acc = sB2[o];
#pragma unroll
    for (int k = 0; k < 64; ++k) acc = fmaf(a1[k], sW2[k * 64 + o], acc);
    a2[o] = fmaxf(acc, 0.0f);
  }
  float r[32];
#pragma unroll
  for (int o = 0; o < 32; ++o) {
    float acc = sBr1[o];
#pragma unroll
    for (int k = 0; k < 64; ++k) acc = fmaf(a2[k], sWr1[k * 32 + o], acc);
    r[o] = fmaxf(acc, 0.0f);
  }
  float acc = sBr2;
#pragma unroll
  for (int k = 0; k < 32; ++k) acc = fmaf(r[k], sWr2[k], acc);
  raw[i] = acc;
}

// ---------- Fused segment softmax: one block per graph (batch is sorted) -----
__device__ __forceinline__ int lowerb(const int* __restrict__ a, int n, int key) {
  int lo = 0, hi = n;
  while (lo < hi) { int mid = (lo + hi) >> 1; if (a[mid] < key) lo = mid + 1; else hi = mid; }
  return lo;
}

__global__ void segsoftmax_kernel(const float* __restrict__ raw, const int* __restrict__ batch,
                                  const float* __restrict__ Btot, float* __restrict__ out, int N) {
  __shared__ float sred[256];
  int g = blockIdx.x;
  int tid = threadIdx.x;
  int start = lowerb(batch, N, g);
  int end = lowerb(batch, N, g + 1);
  if (start >= end) return;

  float m = -FLT_MAX;
  for (int i = start + tid; i < end; i += 256) m = fmaxf(m, raw[i]);
  sred[tid] = m;
  __syncthreads();
  for (int s = 128; s > 0; s >>= 1) {
    if (tid < s) sred[tid] = fmaxf(sred[tid], sred[tid + s]);
    __syncthreads();
  }
  m = sred[0];
  __syncthreads();

  float sum = 0.0f;
  for (int i = start + tid; i < end; i += 256) sum += expf(raw[i] - m);
  sred[tid] = sum;
  __syncthreads();
  for (int s = 128; s > 0; s >>= 1) {
    if (tid < s) sred[tid] += sred[tid + s];
    __syncthreads();
  }
  float scale = Btot[g] / sred[0];

  for (int i = start + tid; i < end; i += 256) out[i] = expf(raw[i] - m) * scale;
}

extern "C" void kernel_launch(void* const* d_in, const int* in_sizes, int n_in,
                              void* d_out, int out_size, void* d_ws, size_t ws_size,
                              hipStream_t stream) {
  const float* x     = (const float*)d_in[0];
  const int* eidx    = (const int*)d_in[1];
  const float* eattr = (const float*)d_in[2];
  const int* batch   = (const int*)d_in[3];
  const float* Btot  = (const float*)d_in[4];
  const float* we1 = (const float*)d_in[5];
  const float* be1 = (const float*)d_in[6];
  const float* w11 = (const float*)d_in[7];
  const float* b11 = (const float*)d_in[8];
  const float* w12 = (const float*)d_in[9];
  const float* b12 = (const float*)d_in[10];
  const float* we2 = (const float*)d_in[11];
  const float* be2 = (const float*)d_in[12];
  const float* w21 = (const float*)d_in[13];
  const float* b21 = (const float*)d_in[14];
  const float* w22 = (const float*)d_in[15];
  const float* b22 = (const float*)d_in[16];
  const float* wr1 = (const float*)d_in[17];
  const float* br1 = (const float*)d_in[18];
  const float* wr2 = (const float*)d_in[19];
  const float* br2 = (const float*)d_in[20];

  const int N  = in_sizes[0] / 9;     // 100000
  const int E  = in_sizes[2];         // 1600000
  const int NG = in_sizes[4];         // 1000
  const int* src = eidx;
  const int* dst = eidx + E;

  const int NB = (N + 1023) / 1024;   // scan blocks (98)

  // workspace layout
  char* w = (char*)d_ws;
  int*   deg    = (int*)w;                 w += (size_t)N * 4;
  int*   rowptr = (int*)w;                 w += (size_t)(N + 1) * 4;
  int*   blocksum = (int*)w;               w += (size_t)1024 * 4;
  int*   rank   = (int*)w;                 w += (size_t)E * 4;
  int*   seid   = (int*)w;                 w += (size_t)E * 4;
  float* h1     = (float*)w;               w += (size_t)N * 64 * 4;
  float* agg2   = (float*)w;               w += (size_t)N * 64 * 4;
  float* raw    = (float*)w;               w += (size_t)N * 4;
  float* xin = agg2;  // aliases agg2 (dead until gather2 fully overwrites)

  hipMemsetAsync(deg, 0, (size_t)N * 4, stream);

  dim3 blk(256);
  dim3 egrid((E + 255) / 256);
  dim3 ngrid((N + 255) / 256);

  deg_rank_kernel<<<egrid, blk, 0, stream>>>(dst, deg, rank, E);
  scan_pass1<<<dim3(NB), dim3(1024), 0, stream>>>(deg, blocksum, N);
  scan_pass2<<<dim3(1), dim3(1024), 0, stream>>>(blocksum, NB);
  scan_pass3<<<dim3(NB), dim3(1024), 0, stream>>>(deg, blocksum, rowptr, N, E);
  scatter_kernel<<<egrid, blk, 0, stream>>>(dst, rank, rowptr, seid, E);

  gather1_kernel<<<ngrid, blk, 0, stream>>>(x, rowptr, seid, src, eattr, we1, be1, xin, N);
  node1_mlp<<<ngrid, blk, 0, stream>>>(xin, w11, b11, w12, b12, h1, N);

  dim3 l2grid((N + 3) / 4);
  gather2_kernel<<<l2grid, blk, 0, stream>>>(h1, rowptr, seid, src, eattr, we2, be2, agg2, N);
  node2_kernel<<<ngrid, blk, 0, stream>>>(h1, agg2, w21, b21, w22, b22,
                                          wr1, br1, wr2, br2, raw, N);

  segsoftmax_kernel<<<dim3(NG), blk, 0, stream>>>(raw, batch, Btot, (float*)d_out, N);
}

// Round 9
// 426.398 us; speedup vs baseline: 3.3220x; 1.0076x over previous
//
#include <hip/hip_runtime.h>
#include <float.h>

// ---------- CSR build ---------------------------------------------------------
__global__ void deg_rank_kernel(const int* __restrict__ dst, int* __restrict__ deg,
                                int* __restrict__ rank, int E) {
  int j = blockIdx.x * blockDim.x + threadIdx.x;
  if (j < E) rank[j] = atomicAdd(&deg[dst[j]], 1);
}

__global__ void scan_pass1(const int* __restrict__ deg, int* __restrict__ blocksum, int N) {
  __shared__ int sdata[1024];
  int i = blockIdx.x * 1024 + threadIdx.x;
  sdata[threadIdx.x] = (i < N) ? deg[i] : 0;
  __syncthreads();
  for (int s = 512; s > 0; s >>= 1) {
    if (threadIdx.x < s) sdata[threadIdx.x] += sdata[threadIdx.x + s];
    __syncthreads();
  }
  if (threadIdx.x == 0) blocksum[blockIdx.x] = sdata[0];
}

__global__ void scan_pass2(int* __restrict__ blocksum, int nb) {
  __shared__ int sdata[1024];
  int t = threadIdx.x;
  sdata[t] = (t < nb) ? blocksum[t] : 0;
  __syncthreads();
  if (t == 0) {
    int run = 0;
    for (int i = 0; i < nb; ++i) { int v = sdata[i]; sdata[i] = run; run += v; }
  }
  __syncthreads();
  if (t < nb) blocksum[t] = sdata[t];
}

__global__ void scan_pass3(const int* __restrict__ deg, const int* __restrict__ blocksum,
                           int* __restrict__ rowptr, int N, int E) {
  __shared__ int sdata[1024];
  int i = blockIdx.x * 1024 + threadIdx.x;
  int v = (i < N) ? deg[i] : 0;
  sdata[threadIdx.x] = v;
  __syncthreads();
  for (int off = 1; off < 1024; off <<= 1) {
    int t = (threadIdx.x >= off) ? sdata[threadIdx.x - off] : 0;
    __syncthreads();
    sdata[threadIdx.x] += t;
    __syncthreads();
  }
  if (i < N) rowptr[i] = blocksum[blockIdx.x] + sdata[threadIdx.x] - v;  // exclusive
  if (i == 0) rowptr[N] = E;
}

__global__ void scatter_kernel(const int* __restrict__ dst, const int* __restrict__ rank,
                               const int* __restrict__ rowptr, int* __restrict__ seid, int E) {
  int j = blockIdx.x * blockDim.x + threadIdx.x;
  if (j >= E) return;
  seid[rowptr[dst[j]] + rank[j]] = j;
}

// ---------- Layer 1 gather: thread-per-node ----------------------------------
__global__ void __launch_bounds__(256, 8) gather1_kernel(
    const float* __restrict__ x, const int* __restrict__ rowptr,
    const int* __restrict__ seid, const int* __restrict__ src, const float* __restrict__ ea,
    const float* __restrict__ we1, const float* __restrict__ be1,
    float* __restrict__ xin, int N) {
  int i = blockIdx.x * blockDim.x + threadIdx.x;
  if (i >= N) return;
  float we[9], be[9];
#pragma unroll
  for (int f = 0; f < 9; ++f) { we[f] = we1[f]; be[f] = be1[f]; }
  float acc[9];
#pragma unroll
  for (int f = 0; f < 9; ++f) acc[f] = 0.0f;

  int p0 = rowptr[i], p1 = rowptr[i + 1];
  int p = p0;
  for (; p + 1 < p1; p += 2) {
    int e0 = seid[p], e1 = seid[p + 1];
    int s0 = src[e0], s1 = src[e1];
    float a0 = ea[e0], a1 = ea[e1];
    float r0[9], r1[9];
#pragma unroll
    for (int f = 0; f < 9; ++f) r0[f] = x[(size_t)s0 * 9 + f];
#pragma unroll
    for (int f = 0; f < 9; ++f) r1[f] = x[(size_t)s1 * 9 + f];
#pragma unroll
    for (int f = 0; f < 9; ++f) {
      acc[f] += fmaxf(fmaf(a0, we[f], be[f]) + r0[f], 0.0f);
      acc[f] += fmaxf(fmaf(a1, we[f], be[f]) + r1[f], 0.0f);
    }
  }
  for (; p < p1; ++p) {
    int e = seid[p];
    int s = src[e];
    float a = ea[e];
#pragma unroll
    for (int f = 0; f < 9; ++f)
      acc[f] += fmaxf(fmaf(a, we[f], be[f]) + x[(size_t)s * 9 + f], 0.0f);
  }
#pragma unroll
  for (int f = 0; f < 9; ++f) xin[(size_t)i * 9 + f] = x[(size_t)i * 9 + f] + acc[f];
}

// ---------- Layer 1 MLP: writes fp32 h1 AND bf16 copy for gather2 ------------
__global__ void __launch_bounds__(256, 3) node1_mlp(
    const float* __restrict__ xin,
    const float* __restrict__ w11, const float* __restrict__ b11,
    const float* __restrict__ w12, const float* __restrict__ b12,
    float* __restrict__ h1, unsigned short* __restrict__ h1b, int N) {
  __shared__ float sW1[9 * 64];
  __shared__ float sB1[64];
  __shared__ float sW2[64 * 64];
  __shared__ float sB2[64];
  for (int t = threadIdx.x; t < 9 * 64; t += blockDim.x) sW1[t] = w11[t];
  for (int t = threadIdx.x; t < 64; t += blockDim.x) { sB1[t] = b11[t]; sB2[t] = b12[t]; }
  for (int t = threadIdx.x; t < 64 * 64; t += blockDim.x) sW2[t] = w12[t];
  __syncthreads();
  int i = blockIdx.x * blockDim.x + threadIdx.x;
  if (i >= N) return;
  float xv[9];
#pragma unroll
  for (int k = 0; k < 9; ++k) xv[k] = xin[(size_t)i * 9 + k];
  float t1[64];
#pragma unroll
  for (int o = 0; o < 64; ++o) {
    float a = sB1[o];
#pragma unroll
    for (int k = 0; k < 9; ++k) a = fmaf(xv[k], sW1[k * 64 + o], a);
    t1[o] = fmaxf(a, 0.0f);
  }
  for (int o = 0; o < 64; ++o) {
    float a = sB2[o];
#pragma unroll
    for (int k = 0; k < 64; ++k) a = fmaf(t1[k], sW2[k * 64 + o], a);
    float v = fmaxf(a, 0.0f);
    h1[(size_t)i * 64 + o] = v;
    unsigned u = __float_as_uint(v);
    h1b[(size_t)i * 64 + o] = (unsigned short)((u + 0x7FFFu + ((u >> 16) & 1u)) >> 16);  // RNE
  }
}

// ---------- Layer 2 gather: wave-per-node, 16-lanes-per-edge, bf16 rows ------
__device__ __forceinline__ float4 bf4_to_f4(uint2 u) {
  float4 r;
  r.x = __uint_as_float(u.x << 16);
  r.y = __uint_as_float(u.x & 0xFFFF0000u);
  r.z = __uint_as_float(u.y << 16);
  r.w = __uint_as_float(u.y & 0xFFFF0000u);
  return r;
}

__global__ void __launch_bounds__(256, 8) gather2_kernel(
    const unsigned short* __restrict__ h1b, const int* __restrict__ rowptr,
    const int* __restrict__ seid, const int* __restrict__ src, const float* __restrict__ ea,
    const float* __restrict__ we2, const float* __restrict__ be2,
    float* __restrict__ agg2, int N) {
  int wid = threadIdx.x >> 6;
  int lane = threadIdx.x & 63;
  int g = lane >> 4;          // edge group 0..3
  int l = lane & 15;          // sublane: features 4l..4l+3
  int i = blockIdx.x * 4 + wid;
  if (i >= N) return;

  float4 we_l = *(const float4*)(we2 + 4 * l);
  float4 be_l = *(const float4*)(be2 + 4 * l);
  float4 acc = make_float4(0.f, 0.f, 0.f, 0.f);

  int p0 = rowptr[i], p1 = rowptr[i + 1];
  int p = p0 + g;
  for (; p + 4 < p1; p += 8) {
    int e0 = seid[p], e1 = seid[p + 4];
    int s0 = src[e0], s1 = src[e1];
    float a0 = ea[e0], a1 = ea[e1];
    float4 h0 = bf4_to_f4(*(const uint2*)(h1b + (size_t)s0 * 64 + 4 * l));
    float4 hv = bf4_to_f4(*(const uint2*)(h1b + (size_t)s1 * 64 + 4 * l));
    acc.x += fmaxf(fmaf(a0, we_l.x, be_l.x) + h0.x, 0.f);
    acc.y += fmaxf(fmaf(a0, we_l.y, be_l.y) + h0.y, 0.f);
    acc.z += fmaxf(fmaf(a0, we_l.z, be_l.z) + h0.z, 0.f);
    acc.w += fmaxf(fmaf(a0, we_l.w, be_l.w) + h0.w, 0.f);
    acc.x += fmaxf(fmaf(a1, we_l.x, be_l.x) + hv.x, 0.f);
    acc.y += fmaxf(fmaf(a1, we_l.y, be_l.y) + hv.y, 0.f);
    acc.z += fmaxf(fmaf(a1, we_l.z, be_l.z) + hv.z, 0.f);
    acc.w += fmaxf(fmaf(a1, we_l.w, be_l.w) + hv.w, 0.f);
  }
  for (; p < p1; p += 4) {
    int e = seid[p];
    int s = src[e];
    float a = ea[e];
    float4 h = bf4_to_f4(*(const uint2*)(h1b + (size_t)s * 64 + 4 * l));
    acc.x += fmaxf(fmaf(a, we_l.x, be_l.x) + h.x, 0.f);
    acc.y += fmaxf(fmaf(a, we_l.y, be_l.y) + h.y, 0.f);
    acc.z += fmaxf(fmaf(a, we_l.z, be_l.z) + h.z, 0.f);
    acc.w += fmaxf(fmaf(a, we_l.w, be_l.w) + h.w, 0.f);
  }
#pragma unroll
  for (int off = 16; off <= 32; off <<= 1) {
    acc.x += __shfl_xor(acc.x, off);
    acc.y += __shfl_xor(acc.y, off);
    acc.z += __shfl_xor(acc.z, off);
    acc.w += __shfl_xor(acc.w, off);
  }
  if (g == 0) *(float4*)(agg2 + (size_t)i * 64 + 4 * l) = acc;
}

// ---------- Layer 2 node MLP + readout (fully unrolled: no scratch) ----------
__global__ void __launch_bounds__(256, 3) node2_kernel(
    const float* __restrict__ h1, const float* __restrict__ agg2,
    const float* __restrict__ w21, const float* __restrict__ b21,
    const float* __restrict__ w22, const float* __restrict__ b22,
    const float* __restrict__ wr1, const float* __restrict__ br1,
    const float* __restrict__ wr2, const float* __restrict__ br2,
    float* __restrict__ raw, int N) {
  __shared__ float sW1[64 * 64];
  __shared__ float sB1[64];
  __shared__ float sW2[64 * 64];
  __shared__ float sB2[64];
  __shared__ float sWr1[64 * 32];
  __shared__ float sBr1[32];
  __shared__ float sWr2[32];
  __shared__ float sBr2;
  for (int t = threadIdx.x; t < 64 * 64; t += blockDim.x) { sW1[t] = w21[t]; sW2[t] = w22[t]; }
  for (int t = threadIdx.x; t < 64; t += blockDim.x) { sB1[t] = b21[t]; sB2[t] = b22[t]; }
  for (int t = threadIdx.x; t < 64 * 32; t += blockDim.x) sWr1[t] = wr1[t];
  for (int t = threadIdx.x; t < 32; t += blockDim.x) { sBr1[t] = br1[t]; sWr2[t] = wr2[t]; }
  if (threadIdx.x == 0) sBr2 = br2[0];
  __syncthreads();
  int i = blockIdx.x * blockDim.x + threadIdx.x;
  if (i >= N) return;
  float hin[64];
#pragma unroll
  for (int k = 0; k < 64; ++k) hin[k] = h1[(size_t)i * 64 + k] + agg2[(size_t)i * 64 + k];
  float a1[64];
#pragma unroll
  for (int o = 0; o < 64; ++o) {
    float acc = sB1[o];
#pragma unroll
    for (int k = 0; k < 64; ++k) acc = fmaf(hin[k], sW1[k * 64 + o], acc);
    a1[o] = fmaxf(acc, 0.0f);
  }
  float a2[64];
#pragma unroll
  for (int o = 0; o < 64; ++o) {
    float acc = sB2[o];
#pragma unroll
    for (int k = 0; k < 64; ++k) acc = fmaf(a1[k], sW2[k * 64 + o], acc);
    a2[o] = fmaxf(acc, 0.0f);
  }
  float r[32];
#pragma unroll
  for (int o = 0; o < 32; ++o) {
    float acc = sBr1[o];
#pragma unroll
    for (int k = 0; k < 64; ++k) acc = fmaf(a2[k], sWr1[k * 32 + o], acc);
    r[o] = fmaxf(acc, 0.0f);
  }
  float acc = sBr2;
#pragma unroll
  for (int k = 0; k < 32; ++k) acc = fmaf(r[k], sWr2[k], acc);
  raw[i] = acc;
}

// ---------- Fused segment softmax: one block per graph (batch is sorted) -----
__device__ __forceinline__ int lowerb(const int* __restrict__ a, int n, int key) {
  int lo = 0, hi = n;
  while (lo < hi) { int mid = (lo + hi) >> 1; if (a[mid] < key) lo = mid + 1; else hi = mid; }
  return lo;
}

__global__ void segsoftmax_kernel(const float* __restrict__ raw, const int* __restrict__ batch,
                                  const float* __restrict__ Btot, float* __restrict__ out, int N) {
  __shared__ float sred[256];
  int g = blockIdx.x;
  int tid = threadIdx.x;
  int start = lowerb(batch, N, g);
  int end = lowerb(batch, N, g + 1);
  if (start >= end) return;

  float m = -FLT_MAX;
  for (int i = start + tid; i < end; i += 256) m = fmaxf(m, raw[i]);
  sred[tid] = m;
  __syncthreads();
  for (int s = 128; s > 0; s >>= 1) {
    if (tid < s) sred[tid] = fmaxf(sred[tid], sred[tid + s]);
    __syncthreads();
  }
  m = sred[0];
  __syncthreads();

  float sum = 0.0f;
  for (int i = start + tid; i < end; i += 256) sum += expf(raw[i] - m);
  sred[tid] = sum;
  __syncthreads();
  for (int s = 128; s > 0; s >>= 1) {
    if (tid < s) sred[tid] += sred[tid + s];
    __syncthreads();
  }
  float scale = Btot[g] / sred[0];

  for (int i = start + tid; i < end; i += 256) out[i] = expf(raw[i] - m) * scale;
}

extern "C" void kernel_launch(void* const* d_in, const int* in_sizes, int n_in,
                              void* d_out, int out_size, void* d_ws, size_t ws_size,
                              hipStream_t stream) {
  const float* x     = (const float*)d_in[0];
  const int* eidx    = (const int*)d_in[1];
  const float* eattr = (const float*)d_in[2];
  const int* batch   = (const int*)d_in[3];
  const float* Btot  = (const float*)d_in[4];
  const float* we1 = (const float*)d_in[5];
  const float* be1 = (const float*)d_in[6];
  const float* w11 = (const float*)d_in[7];
  const float* b11 = (const float*)d_in[8];
  const float* w12 = (const float*)d_in[9];
  const float* b12 = (const float*)d_in[10];
  const float* we2 = (const float*)d_in[11];
  const float* be2 = (const float*)d_in[12];
  const float* w21 = (const float*)d_in[13];
  const float* b21 = (const float*)d_in[14];
  const float* w22 = (const float*)d_in[15];
  const float* b22 = (const float*)d_in[16];
  const float* wr1 = (const float*)d_in[17];
  const float* br1 = (const float*)d_in[18];
  const float* wr2 = (const float*)d_in[19];
  const float* br2 = (const float*)d_in[20];

  const int N  = in_sizes[0] / 9;     // 100000
  const int E  = in_sizes[2];         // 1600000
  const int NG = in_sizes[4];         // 1000
  const int* src = eidx;
  const int* dst = eidx + E;

  const int NB = (N + 1023) / 1024;   // scan blocks (98)

  // workspace layout
  char* w = (char*)d_ws;
  int*   deg    = (int*)w;                 w += (size_t)N * 4;
  int*   rowptr = (int*)w;                 w += (size_t)(N + 1) * 4;
  int*   blocksum = (int*)w;               w += (size_t)1024 * 4;
  int*   rank   = (int*)w;                 w += (size_t)E * 4;
  int*   seid   = (int*)w;                 w += (size_t)E * 4;
  float* h1     = (float*)w;               w += (size_t)N * 64 * 4;
  unsigned short* h1b = (unsigned short*)w; w += (size_t)N * 64 * 2;
  float* agg2   = (float*)w;               w += (size_t)N * 64 * 4;
  float* raw    = (float*)w;               w += (size_t)N * 4;
  float* xin = agg2;  // aliases agg2 (dead until gather2 fully overwrites)

  hipMemsetAsync(deg, 0, (size_t)N * 4, stream);

  dim3 blk(256);
  dim3 egrid((E + 255) / 256);
  dim3 ngrid((N + 255) / 256);

  deg_rank_kernel<<<egrid, blk, 0, stream>>>(dst, deg, rank, E);
  scan_pass1<<<dim3(NB), dim3(1024), 0, stream>>>(deg, blocksum, N);
  scan_pass2<<<dim3(1), dim3(1024), 0, stream>>>(blocksum, NB);
  scan_pass3<<<dim3(NB), dim3(1024), 0, stream>>>(deg, blocksum, rowptr, N, E);
  scatter_kernel<<<egrid, blk, 0, stream>>>(dst, rank, rowptr, seid, E);

  gather1_kernel<<<ngrid, blk, 0, stream>>>(x, rowptr, seid, src, eattr, we1, be1, xin, N);
  node1_mlp<<<ngrid, blk, 0, stream>>>(xin, w11, b11, w12, b12, h1, h1b, N);

  dim3 l2grid((N + 3) / 4);
  gather2_kernel<<<l2grid, blk, 0, stream>>>(h1b, rowptr, seid, src, eattr, we2, be2, agg2, N);
  node2_kernel<<<ngrid, blk, 0, stream>>>(h1, agg2, w21, b21, w22, b22,
                                          wr1, br1, wr2, br2, raw, N);

  segsoftmax_kernel<<<dim3(NG), blk, 0, stream>>>(raw, batch, Btot, (float*)d_out, N);
}

// Round 10
// 342.138 us; speedup vs baseline: 4.1401x; 1.2463x over previous
//
#include <hip/hip_runtime.h>
#include <float.h>

// ---------- CSR build ---------------------------------------------------------
__global__ void deg_rank_kernel(const int* __restrict__ dst, int* __restrict__ deg,
                                int* __restrict__ rank, int E) {
  int j = blockIdx.x * blockDim.x + threadIdx.x;
  if (j < E) rank[j] = atomicAdd(&deg[dst[j]], 1);
}

__global__ void scan_pass1(const int* __restrict__ deg, int* __restrict__ blocksum, int N) {
  __shared__ int sdata[1024];
  int i = blockIdx.x * 1024 + threadIdx.x;
  sdata[threadIdx.x] = (i < N) ? deg[i] : 0;
  __syncthreads();
  for (int s = 512; s > 0; s >>= 1) {
    if (threadIdx.x < s) sdata[threadIdx.x] += sdata[threadIdx.x + s];
    __syncthreads();
  }
  if (threadIdx.x == 0) blocksum[blockIdx.x] = sdata[0];
}

__global__ void scan_pass2(int* __restrict__ blocksum, int nb) {
  __shared__ int sdata[1024];
  int t = threadIdx.x;
  sdata[t] = (t < nb) ? blocksum[t] : 0;
  __syncthreads();
  if (t == 0) {
    int run = 0;
    for (int i = 0; i < nb; ++i) { int v = sdata[i]; sdata[i] = run; run += v; }
  }
  __syncthreads();
  if (t < nb) blocksum[t] = sdata[t];
}

__global__ void scan_pass3(const int* __restrict__ deg, const int* __restrict__ blocksum,
                           int* __restrict__ rowptr, int N, int E) {
  __shared__ int sdata[1024];
  int i = blockIdx.x * 1024 + threadIdx.x;
  int v = (i < N) ? deg[i] : 0;
  sdata[threadIdx.x] = v;
  __syncthreads();
  for (int off = 1; off < 1024; off <<= 1) {
    int t = (threadIdx.x >= off) ? sdata[threadIdx.x - off] : 0;
    __syncthreads();
    sdata[threadIdx.x] += t;
    __syncthreads();
  }
  if (i < N) rowptr[i] = blocksum[blockIdx.x] + sdata[threadIdx.x] - v;  // exclusive
  if (i == 0) rowptr[N] = E;
}

// scatter the full edge payload {src, ea} in CSR order (atomic-free).
// src/ea reads are coalesced by j; only the 8B store is random.
__global__ void scatter_kernel(const int* __restrict__ dst, const int* __restrict__ rank,
                               const int* __restrict__ rowptr,
                               const int* __restrict__ src, const float* __restrict__ ea,
                               int2* __restrict__ epack, int E) {
  int j = blockIdx.x * blockDim.x + threadIdx.x;
  if (j >= E) return;
  int pos = rowptr[dst[j]] + rank[j];
  epack[pos] = make_int2(src[j], __float_as_int(ea[j]));
}

// ---------- Layer 1 gather: thread-per-node, sequential epack ----------------
__global__ void __launch_bounds__(256, 8) gather1_kernel(
    const float* __restrict__ x, const int* __restrict__ rowptr,
    const int2* __restrict__ epack,
    const float* __restrict__ we1, const float* __restrict__ be1,
    float* __restrict__ xin, int N) {
  int i = blockIdx.x * blockDim.x + threadIdx.x;
  if (i >= N) return;
  float we[9], be[9];
#pragma unroll
  for (int f = 0; f < 9; ++f) { we[f] = we1[f]; be[f] = be1[f]; }
  float acc[9];
#pragma unroll
  for (int f = 0; f < 9; ++f) acc[f] = 0.0f;

  int p0 = rowptr[i], p1 = rowptr[i + 1];
  int p = p0;
  for (; p + 1 < p1; p += 2) {
    int2 e0 = epack[p], e1 = epack[p + 1];
    float a0 = __int_as_float(e0.y), a1 = __int_as_float(e1.y);
    float r0[9], r1[9];
#pragma unroll
    for (int f = 0; f < 9; ++f) r0[f] = x[(size_t)e0.x * 9 + f];
#pragma unroll
    for (int f = 0; f < 9; ++f) r1[f] = x[(size_t)e1.x * 9 + f];
#pragma unroll
    for (int f = 0; f < 9; ++f) {
      acc[f] += fmaxf(fmaf(a0, we[f], be[f]) + r0[f], 0.0f);
      acc[f] += fmaxf(fmaf(a1, we[f], be[f]) + r1[f], 0.0f);
    }
  }
  for (; p < p1; ++p) {
    int2 e = epack[p];
    float a = __int_as_float(e.y);
#pragma unroll
    for (int f = 0; f < 9; ++f)
      acc[f] += fmaxf(fmaf(a, we[f], be[f]) + x[(size_t)e.x * 9 + f], 0.0f);
  }
#pragma unroll
  for (int f = 0; f < 9; ++f) xin[(size_t)i * 9 + f] = x[(size_t)i * 9 + f] + acc[f];
}

// ---------- Layer 1 MLP: writes fp32 h1 AND bf16 copy for gather2 ------------
__global__ void __launch_bounds__(256, 3) node1_mlp(
    const float* __restrict__ xin,
    const float* __restrict__ w11, const float* __restrict__ b11,
    const float* __restrict__ w12, const float* __restrict__ b12,
    float* __restrict__ h1, unsigned short* __restrict__ h1b, int N) {
  __shared__ float sW1[9 * 64];
  __shared__ float sB1[64];
  __shared__ float sW2[64 * 64];
  __shared__ float sB2[64];
  for (int t = threadIdx.x; t < 9 * 64; t += blockDim.x) sW1[t] = w11[t];
  for (int t = threadIdx.x; t < 64; t += blockDim.x) { sB1[t] = b11[t]; sB2[t] = b12[t]; }
  for (int t = threadIdx.x; t < 64 * 64; t += blockDim.x) sW2[t] = w12[t];
  __syncthreads();
  int i = blockIdx.x * blockDim.x + threadIdx.x;
  if (i >= N) return;
  float xv[9];
#pragma unroll
  for (int k = 0; k < 9; ++k) xv[k] = xin[(size_t)i * 9 + k];
  float t1[64];
#pragma unroll
  for (int o = 0; o < 64; ++o) {
    float a = sB1[o];
#pragma unroll
    for (int k = 0; k < 9; ++k) a = fmaf(xv[k], sW1[k * 64 + o], a);
    t1[o] = fmaxf(a, 0.0f);
  }
  for (int o = 0; o < 64; ++o) {
    float a = sB2[o];
#pragma unroll
    for (int k = 0; k < 64; ++k) a = fmaf(t1[k], sW2[k * 64 + o], a);
    float v = fmaxf(a, 0.0f);
    h1[(size_t)i * 64 + o] = v;
    unsigned u = __float_as_uint(v);
    h1b[(size_t)i * 64 + o] = (unsigned short)((u + 0x7FFFu + ((u >> 16) & 1u)) >> 16);  // RNE
  }
}

// ---------- Layer 2 gather: wave-per-node, 16-lanes-per-edge, bf16 rows ------
__device__ __forceinline__ float4 bf4_to_f4(uint2 u) {
  float4 r;
  r.x = __uint_as_float(u.x << 16);
  r.y = __uint_as_float(u.x & 0xFFFF0000u);
  r.z = __uint_as_float(u.y << 16);
  r.w = __uint_as_float(u.y & 0xFFFF0000u);
  return r;
}

__global__ void __launch_bounds__(256, 8) gather2_kernel(
    const unsigned short* __restrict__ h1b, const int* __restrict__ rowptr,
    const int2* __restrict__ epack,
    const float* __restrict__ we2, const float* __restrict__ be2,
    float* __restrict__ agg2, int N) {
  int wid = threadIdx.x >> 6;
  int lane = threadIdx.x & 63;
  int g = lane >> 4;          // edge group 0..3
  int l = lane & 15;          // sublane: features 4l..4l+3
  int i = blockIdx.x * 4 + wid;
  if (i >= N) return;

  float4 we_l = *(const float4*)(we2 + 4 * l);
  float4 be_l = *(const float4*)(be2 + 4 * l);
  float4 acc = make_float4(0.f, 0.f, 0.f, 0.f);

  int p0 = rowptr[i], p1 = rowptr[i + 1];
  int p = p0 + g;
  for (; p + 4 < p1; p += 8) {
    int2 e0 = epack[p], e1 = epack[p + 4];
    float a0 = __int_as_float(e0.y), a1 = __int_as_float(e1.y);
    float4 h0 = bf4_to_f4(*(const uint2*)(h1b + (size_t)e0.x * 64 + 4 * l));
    float4 hv = bf4_to_f4(*(const uint2*)(h1b + (size_t)e1.x * 64 + 4 * l));
    acc.x += fmaxf(fmaf(a0, we_l.x, be_l.x) + h0.x, 0.f);
    acc.y += fmaxf(fmaf(a0, we_l.y, be_l.y) + h0.y, 0.f);
    acc.z += fmaxf(fmaf(a0, we_l.z, be_l.z) + h0.z, 0.f);
    acc.w += fmaxf(fmaf(a0, we_l.w, be_l.w) + h0.w, 0.f);
    acc.x += fmaxf(fmaf(a1, we_l.x, be_l.x) + hv.x, 0.f);
    acc.y += fmaxf(fmaf(a1, we_l.y, be_l.y) + hv.y, 0.f);
    acc.z += fmaxf(fmaf(a1, we_l.z, be_l.z) + hv.z, 0.f);
    acc.w += fmaxf(fmaf(a1, we_l.w, be_l.w) + hv.w, 0.f);
  }
  for (; p < p1; p += 4) {
    int2 e = epack[p];
    float a = __int_as_float(e.y);
    float4 h = bf4_to_f4(*(const uint2*)(h1b + (size_t)e.x * 64 + 4 * l));
    acc.x += fmaxf(fmaf(a, we_l.x, be_l.x) + h.x, 0.f);
    acc.y += fmaxf(fmaf(a, we_l.y, be_l.y) + h.y, 0.f);
    acc.z += fmaxf(fmaf(a, we_l.z, be_l.z) + h.z, 0.f);
    acc.w += fmaxf(fmaf(a, we_l.w, be_l.w) + h.w, 0.f);
  }
#pragma unroll
  for (int off = 16; off <= 32; off <<= 1) {
    acc.x += __shfl_xor(acc.x, off);
    acc.y += __shfl_xor(acc.y, off);
    acc.z += __shfl_xor(acc.z, off);
    acc.w += __shfl_xor(acc.w, off);
  }
  if (g == 0) *(float4*)(agg2 + (size_t)i * 64 + 4 * l) = acc;
}

// ---------- Layer 2 node MLP + readout (fully unrolled: no scratch) ----------
__global__ void __launch_bounds__(256, 3) node2_kernel(
    const float* __restrict__ h1, const float* __restrict__ agg2,
    const float* __restrict__ w21, const float* __restrict__ b21,
    const float* __restrict__ w22, const float* __restrict__ b22,
    const float* __restrict__ wr1, const float* __restrict__ br1,
    const float* __restrict__ wr2, const float* __restrict__ br2,
    float* __restrict__ raw, int N) {
  __shared__ float sW1[64 * 64];
  __shared__ float sB1[64];
  __shared__ float sW2[64 * 64];
  __shared__ float sB2[64];
  __shared__ float sWr1[64 * 32];
  __shared__ float sBr1[32];
  __shared__ float sWr2[32];
  __shared__ float sBr2;
  for (int t = threadIdx.x; t < 64 * 64; t += blockDim.x) { sW1[t] = w21[t]; sW2[t] = w22[t]; }
  for (int t = threadIdx.x; t < 64; t += blockDim.x) { sB1[t] = b21[t]; sB2[t] = b22[t]; }
  for (int t = threadIdx.x; t < 64 * 32; t += blockDim.x) sWr1[t] = wr1[t];
  for (int t = threadIdx.x; t < 32; t += blockDim.x) { sBr1[t] = br1[t]; sWr2[t] = wr2[t]; }
  if (threadIdx.x == 0) sBr2 = br2[0];
  __syncthreads();
  int i = blockIdx.x * blockDim.x + threadIdx.x;
  if (i >= N) return;
  float hin[64];
#pragma unroll
  for (int k = 0; k < 64; ++k) hin[k] = h1[(size_t)i * 64 + k] + agg2[(size_t)i * 64 + k];
  float a1[64];
#pragma unroll
  for (int o = 0; o < 64; ++o) {
    float acc = sB1[o];
#pragma unroll
    for (int k = 0; k < 64; ++k) acc = fmaf(hin[k], sW1[k * 64 + o], acc);
    a1[o] = fmaxf(acc, 0.0f);
  }
  float a2[64];
#pragma unroll
  for (int o = 0; o < 64; ++o) {
    float acc = sB2[o];
#pragma unroll
    for (int k = 0; k < 64; ++k) acc = fmaf(a1[k], sW2[k * 64 + o], acc);
    a2[o] = fmaxf(acc, 0.0f);
  }
  float r[32];
#pragma unroll
  for (int o = 0; o < 32; ++o) {
    float acc = sBr1[o];
#pragma unroll
    for (int k = 0; k < 64; ++k) acc = fmaf(a2[k], sWr1[k * 32 + o], acc);
    r[o] = fmaxf(acc, 0.0f);
  }
  float acc = sBr2;
#pragma unroll
  for (int k = 0; k < 32; ++k) acc = fmaf(r[k], sWr2[k], acc);
  raw[i] = acc;
}

// ---------- Fused segment softmax: one block per graph (batch is sorted) -----
__device__ __forceinline__ int lowerb(const int* __restrict__ a, int n, int key) {
  int lo = 0, hi = n;
  while (lo < hi) { int mid = (lo + hi) >> 1; if (a[mid] < key) lo = mid + 1; else hi = mid; }
  return lo;
}

__global__ void segsoftmax_kernel(const float* __restrict__ raw, const int* __restrict__ batch,
                                  const float* __restrict__ Btot, float* __restrict__ out, int N) {
  __shared__ float sred[256];
  int g = blockIdx.x;
  int tid = threadIdx.x;
  int start = lowerb(batch, N, g);
  int end = lowerb(batch, N, g + 1);
  if (start >= end) return;

  float m = -FLT_MAX;
  for (int i = start + tid; i < end; i += 256) m = fmaxf(m, raw[i]);
  sred[tid] = m;
  __syncthreads();
  for (int s = 128; s > 0; s >>= 1) {
    if (tid < s) sred[tid] = fmaxf(sred[tid], sred[tid + s]);
    __syncthreads();
  }
  m = sred[0];
  __syncthreads();

  float sum = 0.0f;
  for (int i = start + tid; i < end; i += 256) sum += expf(raw[i] - m);
  sred[tid] = sum;
  __syncthreads();
  for (int s = 128; s > 0; s >>= 1) {
    if (tid < s) sred[tid] += sred[tid + s];
    __syncthreads();
  }
  float scale = Btot[g] / sred[0];

  for (int i = start + tid; i < end; i += 256) out[i] = expf(raw[i] - m) * scale;
}

extern "C" void kernel_launch(void* const* d_in, const int* in_sizes, int n_in,
                              void* d_out, int out_size, void* d_ws, size_t ws_size,
                              hipStream_t stream) {
  const float* x     = (const float*)d_in[0];
  const int* eidx    = (const int*)d_in[1];
  const float* eattr = (const float*)d_in[2];
  const int* batch   = (const int*)d_in[3];
  const float* Btot  = (const float*)d_in[4];
  const float* we1 = (const float*)d_in[5];
  const float* be1 = (const float*)d_in[6];
  const float* w11 = (const float*)d_in[7];
  const float* b11 = (const float*)d_in[8];
  const float* w12 = (const float*)d_in[9];
  const float* b12 = (const float*)d_in[10];
  const float* we2 = (const float*)d_in[11];
  const float* be2 = (const float*)d_in[12];
  const float* w21 = (const float*)d_in[13];
  const float* b21 = (const float*)d_in[14];
  const float* w22 = (const float*)d_in[15];
  const float* b22 = (const float*)d_in[16];
  const float* wr1 = (const float*)d_in[17];
  const float* br1 = (const float*)d_in[18];
  const float* wr2 = (const float*)d_in[19];
  const float* br2 = (const float*)d_in[20];

  const int N  = in_sizes[0] / 9;     // 100000
  const int E  = in_sizes[2];         // 1600000
  const int NG = in_sizes[4];         // 1000
  const int* src = eidx;
  const int* dst = eidx + E;

  const int NB = (N + 1023) / 1024;   // scan blocks (98)

  // workspace layout
  char* w = (char*)d_ws;
  int*   deg    = (int*)w;                 w += (size_t)N * 4;
  int*   rowptr = (int*)w;                 w += (size_t)(N + 1) * 4;
  int*   blocksum = (int*)w;               w += (size_t)1024 * 4;
  int*   rank   = (int*)w;                 w += (size_t)E * 4;
  int2*  epack  = (int2*)w;                w += (size_t)E * 8;
  float* h1     = (float*)w;               w += (size_t)N * 64 * 4;
  unsigned short* h1b = (unsigned short*)w; w += (size_t)N * 64 * 2;
  float* agg2   = (float*)w;               w += (size_t)N * 64 * 4;
  float* raw    = (float*)w;               w += (size_t)N * 4;
  float* xin = agg2;  // aliases agg2 (dead until gather2 fully overwrites)

  hipMemsetAsync(deg, 0, (size_t)N * 4, stream);

  dim3 blk(256);
  dim3 egrid((E + 255) / 256);
  dim3 ngrid((N + 255) / 256);

  deg_rank_kernel<<<egrid, blk, 0, stream>>>(dst, deg, rank, E);
  scan_pass1<<<dim3(NB), dim3(1024), 0, stream>>>(deg, blocksum, N);
  scan_pass2<<<dim3(1), dim3(1024), 0, stream>>>(blocksum, NB);
  scan_pass3<<<dim3(NB), dim3(1024), 0, stream>>>(deg, blocksum, rowptr, N, E);
  scatter_kernel<<<egrid, blk, 0, stream>>>(dst, rank, rowptr, src, eattr, epack, E);

  gather1_kernel<<<ngrid, blk, 0, stream>>>(x, rowptr, epack, we1, be1, xin, N);
  node1_mlp<<<ngrid, blk, 0, stream>>>(xin, w11, b11, w12, b12, h1, h1b, N);

  dim3 l2grid((N + 3) / 4);
  gather2_kernel<<<l2grid, blk, 0, stream>>>(h1b, rowptr, epack, we2, be2, agg2, N);
  node2_kernel<<<ngrid, blk, 0, stream>>>(h1, agg2, w21, b21, w22, b22,
                                          wr1, br1, wr2, br2, raw, N);

  segsoftmax_kernel<<<dim3(NG), blk, 0, stream>>>(raw, batch, Btot, (float*)d_out, N);
}

// Round 11
// 318.411 us; speedup vs baseline: 4.4486x; 1.0745x over previous
//
#include <hip/hip_runtime.h>
#include <float.h>

// ---------- CSR build ---------------------------------------------------------
__global__ void deg_rank_kernel(const int* __restrict__ dst, int* __restrict__ deg,
                                int* __restrict__ rank, int E) {
  int j = blockIdx.x * blockDim.x + threadIdx.x;
  if (j < E) rank[j] = atomicAdd(&deg[dst[j]], 1);
}

__global__ void scan_pass1(const int* __restrict__ deg, int* __restrict__ blocksum, int N) {
  __shared__ int sdata[1024];
  int i = blockIdx.x * 1024 + threadIdx.x;
  sdata[threadIdx.x] = (i < N) ? deg[i] : 0;
  __syncthreads();
  for (int s = 512; s > 0; s >>= 1) {
    if (threadIdx.x < s) sdata[threadIdx.x] += sdata[threadIdx.x + s];
    __syncthreads();
  }
  if (threadIdx.x == 0) blocksum[blockIdx.x] = sdata[0];
}

__global__ void scan_pass2(int* __restrict__ blocksum, int nb) {
  __shared__ int sdata[1024];
  int t = threadIdx.x;
  sdata[t] = (t < nb) ? blocksum[t] : 0;
  __syncthreads();
  if (t == 0) {
    int run = 0;
    for (int i = 0; i < nb; ++i) { int v = sdata[i]; sdata[i] = run; run += v; }
  }
  __syncthreads();
  if (t < nb) blocksum[t] = sdata[t];
}

__global__ void scan_pass3(const int* __restrict__ deg, const int* __restrict__ blocksum,
                           int* __restrict__ rowptr, int N, int E) {
  __shared__ int sdata[1024];
  int i = blockIdx.x * 1024 + threadIdx.x;
  int v = (i < N) ? deg[i] : 0;
  sdata[threadIdx.x] = v;
  __syncthreads();
  for (int off = 1; off < 1024; off <<= 1) {
    int t = (threadIdx.x >= off) ? sdata[threadIdx.x - off] : 0;
    __syncthreads();
    sdata[threadIdx.x] += t;
    __syncthreads();
  }
  if (i < N) rowptr[i] = blocksum[blockIdx.x] + sdata[threadIdx.x] - v;  // exclusive
  if (i == 0) rowptr[N] = E;
}

// scatter the full edge payload {src, ea} in CSR order (atomic-free).
__global__ void scatter_kernel(const int* __restrict__ dst, const int* __restrict__ rank,
                               const int* __restrict__ rowptr,
                               const int* __restrict__ src, const float* __restrict__ ea,
                               int2* __restrict__ epack, int E) {
  int j = blockIdx.x * blockDim.x + threadIdx.x;
  if (j >= E) return;
  int pos = rowptr[dst[j]] + rank[j];
  epack[pos] = make_int2(src[j], __float_as_int(ea[j]));
}

// ---------- Layer 1 gather: thread-per-node, sequential epack ----------------
__global__ void __launch_bounds__(256, 8) gather1_kernel(
    const float* __restrict__ x, const int* __restrict__ rowptr,
    const int2* __restrict__ epack,
    const float* __restrict__ we1, const float* __restrict__ be1,
    float* __restrict__ xin, int N) {
  int i = blockIdx.x * blockDim.x + threadIdx.x;
  if (i >= N) return;
  float we[9], be[9];
#pragma unroll
  for (int f = 0; f < 9; ++f) { we[f] = we1[f]; be[f] = be1[f]; }
  float acc[9];
#pragma unroll
  for (int f = 0; f < 9; ++f) acc[f] = 0.0f;

  int p0 = rowptr[i], p1 = rowptr[i + 1];
  int p = p0;
  for (; p + 1 < p1; p += 2) {
    int2 e0 = epack[p], e1 = epack[p + 1];
    float a0 = __int_as_float(e0.y), a1 = __int_as_float(e1.y);
    float r0[9], r1[9];
#pragma unroll
    for (int f = 0; f < 9; ++f) r0[f] = x[(size_t)e0.x * 9 + f];
#pragma unroll
    for (int f = 0; f < 9; ++f) r1[f] = x[(size_t)e1.x * 9 + f];
#pragma unroll
    for (int f = 0; f < 9; ++f) {
      acc[f] += fmaxf(fmaf(a0, we[f], be[f]) + r0[f], 0.0f);
      acc[f] += fmaxf(fmaf(a1, we[f], be[f]) + r1[f], 0.0f);
    }
  }
  for (; p < p1; ++p) {
    int2 e = epack[p];
    float a = __int_as_float(e.y);
#pragma unroll
    for (int f = 0; f < 9; ++f)
      acc[f] += fmaxf(fmaf(a, we[f], be[f]) + x[(size_t)e.x * 9 + f], 0.0f);
  }
#pragma unroll
  for (int f = 0; f < 9; ++f) xin[(size_t)i * 9 + f] = x[(size_t)i * 9 + f] + acc[f];
}

// ---------- Layer 1 MLP: writes h1 TRANSPOSED [64][N] (coalesced stores) -----
// R10: row-major scalar stores caused 6x partial-sector write amplification
// (246 MB vs 38 MB legit). h1t[o*N+i] makes every store lane-consecutive.
__global__ void __launch_bounds__(256, 3) node1_mlp(
    const float* __restrict__ xin,
    const float* __restrict__ w11, const float* __restrict__ b11,
    const float* __restrict__ w12, const float* __restrict__ b12,
    float* __restrict__ h1t, int N) {
  __shared__ float sW1[9 * 64];
  __shared__ float sB1[64];
  __shared__ float sW2[64 * 64];
  __shared__ float sB2[64];
  for (int t = threadIdx.x; t < 9 * 64; t += blockDim.x) sW1[t] = w11[t];
  for (int t = threadIdx.x; t < 64; t += blockDim.x) { sB1[t] = b11[t]; sB2[t] = b12[t]; }
  for (int t = threadIdx.x; t < 64 * 64; t += blockDim.x) sW2[t] = w12[t];
  __syncthreads();
  int i = blockIdx.x * blockDim.x + threadIdx.x;
  if (i >= N) return;
  float xv[9];
#pragma unroll
  for (int k = 0; k < 9; ++k) xv[k] = xin[(size_t)i * 9 + k];
  float t1[64];
#pragma unroll
  for (int o = 0; o < 64; ++o) {
    float a = sB1[o];
#pragma unroll
    for (int k = 0; k < 9; ++k) a = fmaf(xv[k], sW1[k * 64 + o], a);
    t1[o] = fmaxf(a, 0.0f);
  }
  for (int o = 0; o < 64; ++o) {
    float a = sB2[o];
#pragma unroll
    for (int k = 0; k < 64; ++k) a = fmaf(t1[k], sW2[k * 64 + o], a);
    h1t[(size_t)o * N + i] = fmaxf(a, 0.0f);  // coalesced across lanes
  }
}

// ---------- pack: h1t [64][N] fp32 -> h1b [N][64] bf16 (both sides coalesced) -
__global__ void __launch_bounds__(256) pack_kernel(
    const float* __restrict__ h1t, unsigned short* __restrict__ h1b, int N) {
  __shared__ unsigned short tile[64][72];  // +8 pad: conflict-light, rows 8B-aligned
  int i0 = blockIdx.x * 64;
  int l = threadIdx.x & 63;
  int q = threadIdx.x >> 6;   // 0..3
  int node = i0 + l;
#pragma unroll
  for (int it = 0; it < 16; ++it) {
    int o = it * 4 + q;
    float v = (node < N) ? h1t[(size_t)o * N + node] : 0.0f;
    unsigned u = __float_as_uint(v);
    tile[l][o] = (unsigned short)((u + 0x7FFFu + ((u >> 16) & 1u)) >> 16);  // RNE
  }
  __syncthreads();
#pragma unroll
  for (int it = 0; it < 4; ++it) {
    int idx = it * 256 + threadIdx.x;  // 0..1023
    int r = idx >> 4;                  // node row 0..63
    int c = idx & 15;                  // uint2 chunk (4 bf16) 0..15
    if (i0 + r < N) {
      const unsigned short* tp = &tile[r][c * 4];
      uint2 v;
      v.x = (unsigned)tp[0] | ((unsigned)tp[1] << 16);
      v.y = (unsigned)tp[2] | ((unsigned)tp[3] << 16);
      *(uint2*)(h1b + (size_t)(i0 + r) * 64 + c * 4) = v;
    }
  }
}

// ---------- Layer 2 gather: wave-per-node, 16-lanes-per-edge, bf16 rows ------
__device__ __forceinline__ float4 bf4_to_f4(uint2 u) {
  float4 r;
  r.x = __uint_as_float(u.x << 16);
  r.y = __uint_as_float(u.x & 0xFFFF0000u);
  r.z = __uint_as_float(u.y << 16);
  r.w = __uint_as_float(u.y & 0xFFFF0000u);
  return r;
}

__global__ void __launch_bounds__(256, 8) gather2_kernel(
    const unsigned short* __restrict__ h1b, const int* __restrict__ rowptr,
    const int2* __restrict__ epack,
    const float* __restrict__ we2, const float* __restrict__ be2,
    float* __restrict__ agg2, int N) {
  int wid = threadIdx.x >> 6;
  int lane = threadIdx.x & 63;
  int g = lane >> 4;          // edge group 0..3
  int l = lane & 15;          // sublane: features 4l..4l+3
  int i = blockIdx.x * 4 + wid;
  if (i >= N) return;

  float4 we_l = *(const float4*)(we2 + 4 * l);
  float4 be_l = *(const float4*)(be2 + 4 * l);
  float4 acc = make_float4(0.f, 0.f, 0.f, 0.f);

  int p0 = rowptr[i], p1 = rowptr[i + 1];
  int p = p0 + g;
  for (; p + 4 < p1; p += 8) {
    int2 e0 = epack[p], e1 = epack[p + 4];
    float a0 = __int_as_float(e0.y), a1 = __int_as_float(e1.y);
    float4 h0 = bf4_to_f4(*(const uint2*)(h1b + (size_t)e0.x * 64 + 4 * l));
    float4 hv = bf4_to_f4(*(const uint2*)(h1b + (size_t)e1.x * 64 + 4 * l));
    acc.x += fmaxf(fmaf(a0, we_l.x, be_l.x) + h0.x, 0.f);
    acc.y += fmaxf(fmaf(a0, we_l.y, be_l.y) + h0.y, 0.f);
    acc.z += fmaxf(fmaf(a0, we_l.z, be_l.z) + h0.z, 0.f);
    acc.w += fmaxf(fmaf(a0, we_l.w, be_l.w) + h0.w, 0.f);
    acc.x += fmaxf(fmaf(a1, we_l.x, be_l.x) + hv.x, 0.f);
    acc.y += fmaxf(fmaf(a1, we_l.y, be_l.y) + hv.y, 0.f);
    acc.z += fmaxf(fmaf(a1, we_l.z, be_l.z) + hv.z, 0.f);
    acc.w += fmaxf(fmaf(a1, we_l.w, be_l.w) + hv.w, 0.f);
  }
  for (; p < p1; p += 4) {
    int2 e = epack[p];
    float a = __int_as_float(e.y);
    float4 h = bf4_to_f4(*(const uint2*)(h1b + (size_t)e.x * 64 + 4 * l));
    acc.x += fmaxf(fmaf(a, we_l.x, be_l.x) + h.x, 0.f);
    acc.y += fmaxf(fmaf(a, we_l.y, be_l.y) + h.y, 0.f);
    acc.z += fmaxf(fmaf(a, we_l.z, be_l.z) + h.z, 0.f);
    acc.w += fmaxf(fmaf(a, we_l.w, be_l.w) + h.w, 0.f);
  }
#pragma unroll
  for (int off = 16; off <= 32; off <<= 1) {
    acc.x += __shfl_xor(acc.x, off);
    acc.y += __shfl_xor(acc.y, off);
    acc.z += __shfl_xor(acc.z, off);
    acc.w += __shfl_xor(acc.w, off);
  }
  if (g == 0) *(float4*)(agg2 + (size_t)i * 64 + 4 * l) = acc;
}

// ---------- Layer 2 node MLP + readout (h1 read from transposed h1t) --------
__global__ void __launch_bounds__(256, 3) node2_kernel(
    const float* __restrict__ h1t, const float* __restrict__ agg2,
    const float* __restrict__ w21, const float* __restrict__ b21,
    const float* __restrict__ w22, const float* __restrict__ b22,
    const float* __restrict__ wr1, const float* __restrict__ br1,
    const float* __restrict__ wr2, const float* __restrict__ br2,
    float* __restrict__ raw, int N) {
  __shared__ float sW1[64 * 64];
  __shared__ float sB1[64];
  __shared__ float sW2[64 * 64];
  __shared__ float sB2[64];
  __shared__ float sWr1[64 * 32];
  __shared__ float sBr1[32];
  __shared__ float sWr2[32];
  __shared__ float sBr2;
  for (int t = threadIdx.x; t < 64 * 64; t += blockDim.x) { sW1[t] = w21[t]; sW2[t] = w22[t]; }
  for (int t = threadIdx.x; t < 64; t += blockDim.x) { sB1[t] = b21[t]; sB2[t] = b22[t]; }
  for (int t = threadIdx.x; t < 64 * 32; t += blockDim.x) sWr1[t] = wr1[t];
  for (int t = threadIdx.x; t < 32; t += blockDim.x) { sBr1[t] = br1[t]; sWr2[t] = wr2[t]; }
  if (threadIdx.x == 0) sBr2 = br2[0];
  __syncthreads();
  int i = blockIdx.x * blockDim.x + threadIdx.x;
  if (i >= N) return;
  float hin[64];
#pragma unroll
  for (int k = 0; k < 64; ++k)
    hin[k] = h1t[(size_t)k * N + i] + agg2[(size_t)i * 64 + k];
  float a1[64];
#pragma unroll
  for (int o = 0; o < 64; ++o) {
    float acc = sB1[o];
#pragma unroll
    for (int k = 0; k < 64; ++k) acc = fmaf(hin[k], sW1[k * 64 + o], acc);
    a1[o] = fmaxf(acc, 0.0f);
  }
  float a2[64];
#pragma unroll
  for (int o = 0; o < 64; ++o) {
    float acc = sB2[o];
#pragma unroll
    for (int k = 0; k < 64; ++k) acc = fmaf(a1[k], sW2[k * 64 + o], acc);
    a2[o] = fmaxf(acc, 0.0f);
  }
  float r[32];
#pragma unroll
  for (int o = 0; o < 32; ++o) {
    float acc = sBr1[o];
#pragma unroll
    for (int k = 0; k < 64; ++k) acc = fmaf(a2[k], sWr1[k * 32 + o], acc);
    r[o] = fmaxf(acc, 0.0f);
  }
  float acc = sBr2;
#pragma unroll
  for (int k = 0; k < 32; ++k) acc = fmaf(r[k], sWr2[k], acc);
  raw[i] = acc;
}

// ---------- Fused segment softmax: one block per graph (batch is sorted) -----
__device__ __forceinline__ int lowerb(const int* __restrict__ a, int n, int key) {
  int lo = 0, hi = n;
  while (lo < hi) { int mid = (lo + hi) >> 1; if (a[mid] < key) lo = mid + 1; else hi = mid; }
  return lo;
}

__global__ void segsoftmax_kernel(const float* __restrict__ raw, const int* __restrict__ batch,
                                  const float* __restrict__ Btot, float* __restrict__ out, int N) {
  __shared__ float sred[256];
  int g = blockIdx.x;
  int tid = threadIdx.x;
  int start = lowerb(batch, N, g);
  int end = lowerb(batch, N, g + 1);
  if (start >= end) return;

  float m = -FLT_MAX;
  for (int i = start + tid; i < end; i += 256) m = fmaxf(m, raw[i]);
  sred[tid] = m;
  __syncthreads();
  for (int s = 128; s > 0; s >>= 1) {
    if (tid < s) sred[tid] = fmaxf(sred[tid], sred[tid + s]);
    __syncthreads();
  }
  m = sred[0];
  __syncthreads();

  float sum = 0.0f;
  for (int i = start + tid; i < end; i += 256) sum += expf(raw[i] - m);
  sred[tid] = sum;
  __syncthreads();
  for (int s = 128; s > 0; s >>= 1) {
    if (tid < s) sred[tid] += sred[tid + s];
    __syncthreads();
  }
  float scale = Btot[g] / sred[0];

  for (int i = start + tid; i < end; i += 256) out[i] = expf(raw[i] - m) * scale;
}

extern "C" void kernel_launch(void* const* d_in, const int* in_sizes, int n_in,
                              void* d_out, int out_size, void* d_ws, size_t ws_size,
                              hipStream_t stream) {
  const float* x     = (const float*)d_in[0];
  const int* eidx    = (const int*)d_in[1];
  const float* eattr = (const float*)d_in[2];
  const int* batch   = (const int*)d_in[3];
  const float* Btot  = (const float*)d_in[4];
  const float* we1 = (const float*)d_in[5];
  const float* be1 = (const float*)d_in[6];
  const float* w11 = (const float*)d_in[7];
  const float* b11 = (const float*)d_in[8];
  const float* w12 = (const float*)d_in[9];
  const float* b12 = (const float*)d_in[10];
  const float* we2 = (const float*)d_in[11];
  const float* be2 = (const float*)d_in[12];
  const float* w21 = (const float*)d_in[13];
  const float* b21 = (const float*)d_in[14];
  const float* w22 = (const float*)d_in[15];
  const float* b22 = (const float*)d_in[16];
  const float* wr1 = (const float*)d_in[17];
  const float* br1 = (const float*)d_in[18];
  const float* wr2 = (const float*)d_in[19];
  const float* br2 = (const float*)d_in[20];

  const int N  = in_sizes[0] / 9;     // 100000
  const int E  = in_sizes[2];         // 1600000
  const int NG = in_sizes[4];         // 1000
  const int* src = eidx;
  const int* dst = eidx + E;

  const int NB = (N + 1023) / 1024;   // scan blocks (98)

  // workspace layout
  char* w = (char*)d_ws;
  int*   deg    = (int*)w;                 w += (size_t)N * 4;
  int*   rowptr = (int*)w;                 w += (size_t)(N + 1) * 4;
  int*   blocksum = (int*)w;               w += (size_t)1024 * 4;
  int*   rank   = (int*)w;                 w += (size_t)E * 4;
  int2*  epack  = (int2*)w;                w += (size_t)E * 8;
  float* h1t    = (float*)w;               w += (size_t)N * 64 * 4;
  unsigned short* h1b = (unsigned short*)w; w += (size_t)N * 64 * 2;
  float* agg2   = (float*)w;               w += (size_t)N * 64 * 4;
  float* raw    = (float*)w;               w += (size_t)N * 4;
  float* xin = agg2;  // aliases agg2 (dead until gather2 fully overwrites)

  hipMemsetAsync(deg, 0, (size_t)N * 4, stream);

  dim3 blk(256);
  dim3 egrid((E + 255) / 256);
  dim3 ngrid((N + 255) / 256);

  deg_rank_kernel<<<egrid, blk, 0, stream>>>(dst, deg, rank, E);
  scan_pass1<<<dim3(NB), dim3(1024), 0, stream>>>(deg, blocksum, N);
  scan_pass2<<<dim3(1), dim3(1024), 0, stream>>>(blocksum, NB);
  scan_pass3<<<dim3(NB), dim3(1024), 0, stream>>>(deg, blocksum, rowptr, N, E);
  scatter_kernel<<<egrid, blk, 0, stream>>>(dst, rank, rowptr, src, eattr, epack, E);

  gather1_kernel<<<ngrid, blk, 0, stream>>>(x, rowptr, epack, we1, be1, xin, N);
  node1_mlp<<<ngrid, blk, 0, stream>>>(xin, w11, b11, w12, b12, h1t, N);
  pack_kernel<<<dim3((N + 63) / 64), blk, 0, stream>>>(h1t, h1b, N);

  dim3 l2grid((N + 3) / 4);
  gather2_kernel<<<l2grid, blk, 0, stream>>>(h1b, rowptr, epack, we2, be2, agg2, N);
  node2_kernel<<<ngrid, blk, 0, stream>>>(h1t, agg2, w21, b21, w22, b22,
                                          wr1, br1, wr2, br2, raw, N);

  segsoftmax_kernel<<<dim3(NG), blk, 0, stream>>>(raw, batch, Btot, (float*)d_out, N);
}